// Round 5
// baseline (402.003 us; speedup 1.0000x reference)
//
#include <hip/hip_runtime.h>

#define N_NODES 100000
#define N_EDGES 1600000
#define F_IN 256
#define HD1 128   // HEADS*HID
#define HEADS 8
#define HID 16
#define NC 16
#define NEG_SLOPE 0.2f

__device__ __forceinline__ float leaky(float x){ return x > 0.f ? x : NEG_SLOPE * x; }
__device__ __forceinline__ unsigned short f2bf(float f){
    unsigned u = __float_as_uint(f);
    u += 0x7fff + ((u >> 16) & 1);       // round-to-nearest-even
    return (unsigned short)(u >> 16);
}
__device__ __forceinline__ float bf2f(unsigned short s){
    return __uint_as_float((unsigned)s << 16);
}
__device__ __forceinline__ unsigned char f2fp8(float v){
    return (unsigned char)(__builtin_amdgcn_cvt_pk_fp8_f32(v, v, 0, false) & 0xff);
}

typedef __bf16 bf16x8 __attribute__((ext_vector_type(8)));
typedef short short8 __attribute__((ext_vector_type(8)));
typedef float f32x4 __attribute__((ext_vector_type(4)));

// ---------------- CSR build ----------------

__global__ void __launch_bounds__(256) k_count(const int* __restrict__ dst, int* __restrict__ deg){
    int i = blockIdx.x * 256 + threadIdx.x;
    if (i < N_EDGES) atomicAdd(&deg[dst[i]], 1);
}

#define SCAN_CHUNK 1024
#define SCAN_P ((N_NODES + SCAN_CHUNK - 1) / SCAN_CHUNK)   // 98

__global__ void __launch_bounds__(256) k_scan_partial(const int* __restrict__ deg, int* __restrict__ part){
    __shared__ int red[256];
    int t = threadIdx.x;
    int base = blockIdx.x * SCAN_CHUNK;
    int s = 0;
    for (int i = t; i < SCAN_CHUNK; i += 256){
        int idx = base + i;
        if (idx < N_NODES) s += deg[idx];
    }
    red[t] = s; __syncthreads();
    for (int o = 128; o > 0; o >>= 1){
        if (t < o) red[t] += red[t + o];
        __syncthreads();
    }
    if (t == 0) part[blockIdx.x] = red[0];
}

__global__ void __launch_bounds__(128) k_scan_mid(const int* __restrict__ part, int* __restrict__ pprefix, int* __restrict__ off){
    __shared__ int sd[128];
    int t = threadIdx.x;
    int v = (t < SCAN_P) ? part[t] : 0;
    sd[t] = v; __syncthreads();
    for (int o = 1; o < 128; o <<= 1){
        int add = (t >= o) ? sd[t - o] : 0;
        __syncthreads();
        sd[t] += add;
        __syncthreads();
    }
    if (t < SCAN_P) pprefix[t] = sd[t] - v;   // exclusive prefix of block totals
    if (t == 0) off[N_NODES] = N_EDGES;
}

__global__ void __launch_bounds__(256) k_scan_write(const int* __restrict__ deg, const int* __restrict__ pprefix,
                                                    int* __restrict__ off, int* __restrict__ cursor){
    __shared__ int sd[256];
    int t = threadIdx.x;
    int base = blockIdx.x * SCAN_CHUNK + t * 4;
    int v0 = 0, v1 = 0, v2 = 0, v3 = 0;
    if (base + 0 < N_NODES) v0 = deg[base + 0];
    if (base + 1 < N_NODES) v1 = deg[base + 1];
    if (base + 2 < N_NODES) v2 = deg[base + 2];
    if (base + 3 < N_NODES) v3 = deg[base + 3];
    int tsum = v0 + v1 + v2 + v3;
    sd[t] = tsum; __syncthreads();
    for (int o = 1; o < 256; o <<= 1){
        int add = (t >= o) ? sd[t - o] : 0;
        __syncthreads();
        sd[t] += add;
        __syncthreads();
    }
    int tpre = sd[t] - tsum + pprefix[blockIdx.x];
    int e0 = tpre, e1 = e0 + v0, e2 = e1 + v1, e3 = e2 + v2;
    if (base + 0 < N_NODES){ off[base + 0] = e0; cursor[base + 0] = e0; }
    if (base + 1 < N_NODES){ off[base + 1] = e1; cursor[base + 1] = e1; }
    if (base + 2 < N_NODES){ off[base + 2] = e2; cursor[base + 2] = e2; }
    if (base + 3 < N_NODES){ off[base + 3] = e3; cursor[base + 3] = e3; }
}

__global__ void __launch_bounds__(256) k_scatter(const int* __restrict__ src, const int* __restrict__ dst,
                                                 int* __restrict__ cursor, int* __restrict__ csr_src){
    int i = blockIdx.x * 256 + threadIdx.x;
    if (i < N_EDGES){
        int p = atomicAdd(&cursor[dst[i]], 1);
        csr_src[p] = src[i];
    }
}

// ---------------- W1 split (fp32 -> bf16 hi/lo), transpose + XOR-swizzle ----------------

__global__ void __launch_bounds__(256) k_splitW(const float* __restrict__ W1,
                                                short* __restrict__ WTH, short* __restrict__ WTL){
    int i = blockIdx.x * 256 + threadIdx.x;   // 32768 elems
    if (i >= F_IN * HD1) return;
    int k = i >> 7, n = i & 127;
    float v = W1[i];
    unsigned u = __float_as_uint(v);
    short hs = (short)(u >> 16);
    float lo = v - __uint_as_float(u & 0xffff0000u);
    short ls = (short)(__float_as_uint(lo) >> 16);
    int idx = n * 256 + (k ^ ((n & 7) << 3));
    WTH[idx] = hs;
    WTL[idx] = ls;
}

// ---------------- GEMM1 (MFMA bf16x2): h1f8 = fp8(feat @ W1) ----------------

__device__ __forceinline__ void split8(float4 f0, float4 f1, short8& h, short8& l){
    float f[8] = {f0.x, f0.y, f0.z, f0.w, f1.x, f1.y, f1.z, f1.w};
    #pragma unroll
    for (int i = 0; i < 8; i++){
        unsigned u = __float_as_uint(f[i]);
        h[i] = (short)(u >> 16);
        float lo = f[i] - __uint_as_float(u & 0xffff0000u);
        l[i] = (short)(__float_as_uint(lo) >> 16);
    }
}

__global__ void __launch_bounds__(256, 2) k_gemm1m(const float* __restrict__ feat,
                                                   const short* __restrict__ WTH, const short* __restrict__ WTL,
                                                   unsigned char* __restrict__ h1f8){
    __shared__ short sWH[64 * 256];
    __shared__ short sWL[64 * 256];
    int t = threadIdx.x;
    int ch = blockIdx.y;
    {
        const short8* gh = (const short8*)(WTH + (size_t)ch * 16384);
        const short8* gl = (const short8*)(WTL + (size_t)ch * 16384);
        short8* sh = (short8*)sWH;
        short8* sl = (short8*)sWL;
        for (int i = t; i < 2048; i += 256){ sh[i] = gh[i]; sl[i] = gl[i]; }
    }
    __syncthreads();

    int wid = t >> 6, lane = t & 63;
    int m16 = lane & 15, kg = lane >> 4;
    int rowb = blockIdx.x * 128 + wid * 32;

    f32x4 acc[2][4];
    #pragma unroll
    for (int a = 0; a < 2; a++)
        #pragma unroll
        for (int b = 0; b < 4; b++)
            acc[a][b] = (f32x4){0.f, 0.f, 0.f, 0.f};

    int r0 = rowb + m16;       if (r0 > N_NODES - 1) r0 = N_NODES - 1;
    int r1 = rowb + 16 + m16;  if (r1 > N_NODES - 1) r1 = N_NODES - 1;
    const float* fp0 = feat + (size_t)r0 * F_IN;
    const float* fp1 = feat + (size_t)r1 * F_IN;

    #pragma unroll
    for (int ks = 0; ks < 8; ks++){
        int kbase = ks * 32 + kg * 8;
        short8 ah[2], al[2];
        {
            const float4* p = (const float4*)(fp0 + kbase);
            split8(p[0], p[1], ah[0], al[0]);
        }
        {
            const float4* p = (const float4*)(fp1 + kbase);
            split8(p[0], p[1], ah[1], al[1]);
        }
        bf16x8 AH0 = __builtin_bit_cast(bf16x8, ah[0]);
        bf16x8 AH1 = __builtin_bit_cast(bf16x8, ah[1]);
        bf16x8 AL0 = __builtin_bit_cast(bf16x8, al[0]);
        bf16x8 AL1 = __builtin_bit_cast(bf16x8, al[1]);
        #pragma unroll
        for (int c = 0; c < 4; c++){
            int n = (c << 4) + m16;
            int kk = kbase ^ ((n & 7) << 3);
            bf16x8 bh = __builtin_bit_cast(bf16x8, *(const short8*)(sWH + n * 256 + kk));
            bf16x8 bl = __builtin_bit_cast(bf16x8, *(const short8*)(sWL + n * 256 + kk));
            acc[0][c] = __builtin_amdgcn_mfma_f32_16x16x32_bf16(AH0, bh, acc[0][c], 0, 0, 0);
            acc[1][c] = __builtin_amdgcn_mfma_f32_16x16x32_bf16(AH1, bh, acc[1][c], 0, 0, 0);
            acc[0][c] = __builtin_amdgcn_mfma_f32_16x16x32_bf16(AH0, bl, acc[0][c], 0, 0, 0);
            acc[1][c] = __builtin_amdgcn_mfma_f32_16x16x32_bf16(AH1, bl, acc[1][c], 0, 0, 0);
            acc[0][c] = __builtin_amdgcn_mfma_f32_16x16x32_bf16(AL0, bh, acc[0][c], 0, 0, 0);
            acc[1][c] = __builtin_amdgcn_mfma_f32_16x16x32_bf16(AL1, bh, acc[1][c], 0, 0, 0);
        }
    }

    #pragma unroll
    for (int rf = 0; rf < 2; rf++){
        #pragma unroll
        for (int c = 0; c < 4; c++){
            #pragma unroll
            for (int r = 0; r < 4; r++){
                int row = rowb + rf * 16 + kg * 4 + r;
                if (row < N_NODES){
                    int col = ch * 64 + c * 16 + m16;
                    h1f8[(size_t)row * HD1 + col] = f2fp8(acc[rf][c][r]);
                }
            }
        }
    }
}

// ---------------- el1/er1 from h1f8 (el1 stored bf16, er1 fp32) ----------------

__global__ void __launch_bounds__(256) k_attn1(const unsigned char* __restrict__ h1f8,
                                               const float* __restrict__ al1, const float* __restrict__ ar1,
                                               unsigned short* __restrict__ el1b, float* __restrict__ er1){
    int i = blockIdx.x * 256 + threadIdx.x;
    if (i >= N_NODES * HEADS) return;
    int n = i >> 3, h = i & 7;
    const unsigned* hp = (const unsigned*)(h1f8 + (size_t)n * HD1 + h * HID);
    float pe = 0.f, pr = 0.f;
    #pragma unroll
    for (int j = 0; j < 4; j++){
        unsigned u = hp[j];
        float x0 = __builtin_amdgcn_cvt_f32_fp8(u, 0);
        float x1 = __builtin_amdgcn_cvt_f32_fp8(u, 1);
        float x2 = __builtin_amdgcn_cvt_f32_fp8(u, 2);
        float x3 = __builtin_amdgcn_cvt_f32_fp8(u, 3);
        const float4 a = ((const float4*)(al1 + h * HID))[j];
        const float4 r = ((const float4*)(ar1 + h * HID))[j];
        pe += x0 * a.x + x1 * a.y + x2 * a.z + x3 * a.w;
        pr += x0 * r.x + x1 * r.y + x2 * r.z + x3 * r.w;
    }
    el1b[i] = f2bf(pe);
    er1[i] = pr;
}

// ---------------- Layer-1 aggregation: one wave per dst node, 2 edges/iter, fp8 payload ----------------

__global__ void __launch_bounds__(256) k_agg1(const int* __restrict__ off, const int* __restrict__ csr_src,
                                              const unsigned short* __restrict__ el1b,
                                              const float* __restrict__ er1,
                                              const unsigned char* __restrict__ h1f8,
                                              const float* __restrict__ b1,
                                              unsigned short* __restrict__ x2b){
    int wid = threadIdx.x >> 6, lane = threadIdx.x & 63;
    int n = blockIdx.x * 4 + wid;
    if (n >= N_NODES) return;
    int jb = off[n], je = off[n + 1];
    int q = lane & 31;
    int half = lane >> 5;
    int hh = q >> 2;                       // head for my 4 columns
    float ern = er1[n * HEADS + hh];
    float acc0 = 0.f, acc1 = 0.f, acc2 = 0.f, acc3 = 0.f, wsum = 0.f;

    #pragma unroll 2
    for (int j = jb; j < je; j += 2){
        int j1 = (j + 1 < je) ? j + 1 : j;
        int jj = half ? j1 : j;
        int s = csr_src[jj];
        float el = bf2f(el1b[(size_t)s * HEADS + hh]);
        float wv = __expf(leaky(el + ern));
        if (half && (j + 1 >= je)) wv = 0.f;
        unsigned u = *(const unsigned*)(h1f8 + (size_t)s * HD1 + q * 4);
        float v0 = __builtin_amdgcn_cvt_f32_fp8(u, 0);
        float v1 = __builtin_amdgcn_cvt_f32_fp8(u, 1);
        float v2 = __builtin_amdgcn_cvt_f32_fp8(u, 2);
        float v3 = __builtin_amdgcn_cvt_f32_fp8(u, 3);
        acc0 += wv * v0;
        acc1 += wv * v1;
        acc2 += wv * v2;
        acc3 += wv * v3;
        wsum += wv;
    }

    // combine halves
    acc0 += __shfl_xor(acc0, 32);
    acc1 += __shfl_xor(acc1, 32);
    acc2 += __shfl_xor(acc2, 32);
    acc3 += __shfl_xor(acc3, 32);
    wsum += __shfl_xor(wsum, 32);

    if (half == 0){
        float inv = (je > jb) ? 1.f / wsum : 0.f;
        float o0 = acc0 * inv, o1 = acc1 * inv, o2 = acc2 * inv, o3 = acc3 * inv;
        float4 bv = *(const float4*)(b1 + q * 4);
        o0 += bv.x; o1 += bv.y; o2 += bv.z; o3 += bv.w;
        o0 = o0 > 0.f ? o0 : __expf(o0) - 1.f;
        o1 = o1 > 0.f ? o1 : __expf(o1) - 1.f;
        o2 = o2 > 0.f ? o2 : __expf(o2) - 1.f;
        o3 = o3 > 0.f ? o3 : __expf(o3) - 1.f;
        ushort4 ov = { f2bf(o0), f2bf(o1), f2bf(o2), f2bf(o3) };
        *(ushort4*)(x2b + (size_t)n * HD1 + q * 4) = ov;
    }
}

// ---------------- GEMM2: h2b = bf16(x2 @ W2), fused el2/er2 ----------------

__global__ void __launch_bounds__(256) k_gemm2(const unsigned short* __restrict__ x2b, const float* __restrict__ W2,
                                               const float* __restrict__ al2, const float* __restrict__ ar2,
                                               unsigned short* __restrict__ h2b, float* __restrict__ el2, float* __restrict__ er2){
    __shared__ float sW[HD1 * NC];   // 8 KB
    __shared__ float sX[16 * HD1];   // 8 KB
    int t = threadIdx.x;
    for (int i = t; i < (HD1 * NC) / 4; i += 256)
        ((float4*)sW)[i] = ((const float4*)W2)[i];
    int r = t >> 4, c = t & 15;
    float a2 = al2[c], r2 = ar2[c];
    for (int g = blockIdx.x; g * 16 < N_NODES; g += gridDim.x){
        int rowb = g * 16;
        __syncthreads();
        {
            ushort4 v = ((const ushort4*)(x2b + (size_t)rowb * HD1))[t * 2];
            ushort4 v2 = ((const ushort4*)(x2b + (size_t)rowb * HD1))[t * 2 + 1];
            float4 f0 = { bf2f(v.x), bf2f(v.y), bf2f(v.z), bf2f(v.w) };
            float4 f1 = { bf2f(v2.x), bf2f(v2.y), bf2f(v2.z), bf2f(v2.w) };
            ((float4*)sX)[t * 2] = f0;
            ((float4*)sX)[t * 2 + 1] = f1;
        }
        __syncthreads();
        float acc = 0.f;
        #pragma unroll 8
        for (int k = 0; k < HD1; k++)
            acc += sX[r * HD1 + k] * sW[k * NC + c];
        int row = rowb + r;
        h2b[row * NC + c] = f2bf(acc);
        float pe = acc * a2, pr = acc * r2;
        #pragma unroll
        for (int d = 1; d < 16; d <<= 1){ pe += __shfl_xor(pe, d); pr += __shfl_xor(pr, d); }
        if (c == 0){ el2[row] = pe; er2[row] = pr; }
    }
}

// ---------------- Layer-2 aggregation + bias + log_softmax ----------------

__global__ void __launch_bounds__(256) k_agg2(const int* __restrict__ off, const int* __restrict__ csr_src,
                                              const float* __restrict__ el2, const float* __restrict__ er2,
                                              const unsigned short* __restrict__ h2b, const float* __restrict__ b2,
                                              float* __restrict__ out){
    int t = threadIdx.x;
    int sub = t >> 4;          // 16 nodes per block
    int c = t & 15;
    int n = blockIdx.x * 16 + sub;
    if (n >= N_NODES) return;
    int jb = off[n], je = off[n + 1];
    float er = er2[n];
    float accA = 0.f, accB = 0.f, wsA = 0.f, wsB = 0.f;
    int j = jb;
    for (; j + 1 < je; j += 2){
        int s0 = csr_src[j];
        int s1 = csr_src[j + 1];
        float w0 = __expf(leaky(el2[s0] + er));
        float w1 = __expf(leaky(el2[s1] + er));
        float v0 = bf2f(h2b[(size_t)s0 * NC + c]);
        float v1 = bf2f(h2b[(size_t)s1 * NC + c]);
        wsA += w0; accA += w0 * v0;
        wsB += w1; accB += w1 * v1;
    }
    if (j < je){
        int s0 = csr_src[j];
        float w0 = __expf(leaky(el2[s0] + er));
        wsA += w0; accA += w0 * bf2f(h2b[(size_t)s0 * NC + c]);
    }
    float acc = accA + accB, wsum = wsA + wsB;
    float o = (je > jb) ? acc / wsum : 0.f;
    o += b2[c];
    // log_softmax over the 16 classes (16-lane group)
    float m = o;
    #pragma unroll
    for (int d = 1; d < 16; d <<= 1) m = fmaxf(m, __shfl_xor(m, d));
    float ex = __expf(o - m);
    #pragma unroll
    for (int d = 1; d < 16; d <<= 1) ex += __shfl_xor(ex, d);
    out[(size_t)n * NC + c] = o - m - __logf(ex);
}

// ---------------- launch ----------------

extern "C" void kernel_launch(void* const* d_in, const int* in_sizes, int n_in,
                              void* d_out, int out_size, void* d_ws, size_t ws_size,
                              hipStream_t stream){
    const float* feat = (const float*)d_in[0];
    const int*   src  = (const int*)d_in[1];
    const int*   dst  = (const int*)d_in[2];
    const float* W1   = (const float*)d_in[3];
    const float* al1  = (const float*)d_in[4];
    const float* ar1  = (const float*)d_in[5];
    const float* b1   = (const float*)d_in[6];
    const float* W2   = (const float*)d_in[7];
    const float* al2  = (const float*)d_in[8];
    const float* ar2  = (const float*)d_in[9];
    const float* b2   = (const float*)d_in[10];
    float* out = (float*)d_out;

    char* w = (char*)d_ws;
    auto alloc = [&](size_t bytes) -> char* {
        char* p = w;
        w += (bytes + 255) & ~(size_t)255;
        return p;
    };
    int*   deg     = (int*)alloc((size_t)N_NODES * 4);
    int*   off     = (int*)alloc((size_t)(N_NODES + 1) * 4);
    int*   cursor  = (int*)alloc((size_t)N_NODES * 4);
    int*   part    = (int*)alloc((size_t)SCAN_P * 4);
    int*   pprefix = (int*)alloc((size_t)SCAN_P * 4);
    int*   csr_src = (int*)alloc((size_t)N_EDGES * 4);
    unsigned char*  h1f8 = (unsigned char*)alloc((size_t)N_NODES * HD1);
    unsigned short* el1b = (unsigned short*)alloc((size_t)N_NODES * HEADS * 2);
    float* er1v    = (float*)alloc((size_t)N_NODES * HEADS * 4);
    unsigned short* x2b = (unsigned short*)alloc((size_t)N_NODES * HD1 * 2);
    unsigned short* h2b = (unsigned short*)alloc((size_t)N_NODES * NC * 2);
    float* el2v    = (float*)alloc((size_t)N_NODES * 4);
    float* er2v    = (float*)alloc((size_t)N_NODES * 4);
    short* WTH     = (short*)alloc((size_t)F_IN * HD1 * 2);
    short* WTL     = (short*)alloc((size_t)F_IN * HD1 * 2);

    // CSR degree+scan
    hipMemsetAsync(deg, 0, (size_t)N_NODES * 4, stream);
    k_count<<<(N_EDGES + 255) / 256, 256, 0, stream>>>(dst, deg);
    k_scan_partial<<<SCAN_P, 256, 0, stream>>>(deg, part);
    k_scan_mid<<<1, 128, 0, stream>>>(part, pprefix, off);
    k_scan_write<<<SCAN_P, 256, 0, stream>>>(deg, pprefix, off, cursor);
    k_scatter<<<(N_EDGES + 255) / 256, 256, 0, stream>>>(src, dst, cursor, csr_src);

    // Layer 1 compute
    k_splitW<<<(F_IN * HD1 + 255) / 256, 256, 0, stream>>>(W1, WTH, WTL);
    dim3 g1((N_NODES + 127) / 128, 2);
    k_gemm1m<<<g1, 256, 0, stream>>>(feat, WTH, WTL, h1f8);
    k_attn1<<<(N_NODES * HEADS + 255) / 256, 256, 0, stream>>>(h1f8, al1, ar1, el1b, er1v);

    // Layer-1 aggregation
    k_agg1<<<(N_NODES + 3) / 4, 256, 0, stream>>>(off, csr_src, el1b, er1v, h1f8, b1, x2b);

    // Layer 2
    k_gemm2<<<1024, 256, 0, stream>>>(x2b, W2, al2, ar2, h2b, el2v, er2v);
    k_agg2<<<(N_NODES + 15) / 16, 256, 0, stream>>>(off, csr_src, el2v, er2v, h2b, b2, out);
}

// Round 6
// 258.789 us; speedup vs baseline: 1.5534x; 1.5534x over previous
//
#include <hip/hip_runtime.h>

#define N_NODES 100000
#define N_EDGES 1600000
#define F_IN 256
#define HD1 128   // HEADS*HID
#define HEADS 8
#define HID 16
#define NC 16
#define NEG_SLOPE 0.2f

// ---- bucketed CSR build params ----
#define BKT_NODES 512
#define NBKT ((N_NODES + BKT_NODES - 1) / BKT_NODES)   // 196
#define P1_EPB 8192
#define P1_BLOCKS ((N_EDGES + P1_EPB - 1) / P1_EPB)    // 196

__device__ __forceinline__ float leaky(float x){ return x > 0.f ? x : NEG_SLOPE * x; }
__device__ __forceinline__ unsigned short f2bf(float f){
    unsigned u = __float_as_uint(f);
    u += 0x7fff + ((u >> 16) & 1);       // round-to-nearest-even
    return (unsigned short)(u >> 16);
}
__device__ __forceinline__ float bf2f(unsigned short s){
    return __uint_as_float((unsigned)s << 16);
}
__device__ __forceinline__ unsigned char f2fp8(float v){
    return (unsigned char)(__builtin_amdgcn_cvt_pk_fp8_f32(v, v, 0, false) & 0xff);
}

typedef __bf16 bf16x8 __attribute__((ext_vector_type(8)));
typedef short short8 __attribute__((ext_vector_type(8)));
typedef float f32x4 __attribute__((ext_vector_type(4)));

// ---------------- CSR build: bucketed, no random global scatter ----------------

__global__ void __launch_bounds__(256) k_p1hist(const int* __restrict__ dst, int* __restrict__ bucketTotal){
    __shared__ int h[NBKT];
    int t = threadIdx.x;
    for (int i = t; i < NBKT; i += 256) h[i] = 0;
    __syncthreads();
    int base = blockIdx.x * P1_EPB;
    int m = min(P1_EPB, N_EDGES - base);
    for (int i = t; i < m; i += 256) atomicAdd(&h[(unsigned)dst[base + i] >> 9], 1);
    __syncthreads();
    for (int i = t; i < NBKT; i += 256) if (h[i]) atomicAdd(&bucketTotal[i], h[i]);
}

__global__ void __launch_bounds__(256) k_p1scan(const int* __restrict__ bucketTotal,
                                                int* __restrict__ bucketBase, int* __restrict__ bucketCursor,
                                                int* __restrict__ off){
    __shared__ int sc[256];
    int t = threadIdx.x;
    int v = (t < NBKT) ? bucketTotal[t] : 0;
    sc[t] = v; __syncthreads();
    for (int o = 1; o < 256; o <<= 1){
        int a = (t >= o) ? sc[t - o] : 0;
        __syncthreads();
        sc[t] += a;
        __syncthreads();
    }
    if (t < NBKT){
        int b = sc[t] - v;         // exclusive
        bucketBase[t] = b;
        bucketCursor[t] = b;
    }
    if (t == 0){ bucketBase[NBKT] = N_EDGES; off[N_NODES] = N_EDGES; }
}

__global__ void __launch_bounds__(256) k_p1bin(const int* __restrict__ src, const int* __restrict__ dst,
                                               int* __restrict__ bucketCursor,
                                               unsigned long long* __restrict__ pairs){
    __shared__ unsigned long long pl[P1_EPB];   // 64 KB
    __shared__ int h[NBKT];                     // hist -> running cursor
    __shared__ int dl[NBKT];                    // global-base minus local-base
    __shared__ int sc[256];
    int t = threadIdx.x;
    for (int i = t; i < NBKT; i += 256) h[i] = 0;
    __syncthreads();
    int base = blockIdx.x * P1_EPB;
    int m = min(P1_EPB, N_EDGES - base);
    for (int i = t; i < m; i += 256) atomicAdd(&h[(unsigned)dst[base + i] >> 9], 1);
    __syncthreads();
    int v = (t < NBKT) ? h[t] : 0;
    sc[t] = v; __syncthreads();
    for (int o = 1; o < 256; o <<= 1){
        int a = (t >= o) ? sc[t - o] : 0;
        __syncthreads();
        sc[t] += a;
        __syncthreads();
    }
    if (t < NBKT){
        int ex = sc[t] - v;                        // local exclusive base
        int gb = v ? atomicAdd(&bucketCursor[t], v) : 0;
        dl[t] = gb - ex;
        h[t] = ex;                                 // reuse as running local cursor
    }
    __syncthreads();
    for (int i = t; i < m; i += 256){
        int d = dst[base + i], s = src[base + i];
        int b = (unsigned)d >> 9;
        int p = atomicAdd(&h[b], 1);
        pl[p] = ((unsigned long long)(unsigned)d << 32) | (unsigned)s;
    }
    __syncthreads();
    for (int i = t; i < m; i += 256){
        unsigned long long pr = pl[i];
        int b = (unsigned)(pr >> 32) >> 9;
        pairs[i + dl[b]] = pr;                     // sequential-run writes
    }
}

__global__ void __launch_bounds__(256) k_p2place(const unsigned long long* __restrict__ pairs,
                                                 const int* __restrict__ bucketBase,
                                                 int* __restrict__ off, int* __restrict__ csr_src){
    __shared__ int degc[BKT_NODES];
    __shared__ int sc2[BKT_NODES];
    int t = threadIdx.x;
    int b = blockIdx.x;
    int node0 = b * BKT_NODES;
    int nmax = min(BKT_NODES, N_NODES - node0);
    int p0 = bucketBase[b], p1 = bucketBase[b + 1];
    int m = p1 - p0;
    for (int i = t; i < BKT_NODES; i += 256) degc[i] = 0;
    __syncthreads();
    for (int i = t; i < m; i += 256){
        int d = (int)(pairs[p0 + i] >> 32) - node0;
        atomicAdd(&degc[d], 1);
    }
    __syncthreads();
    for (int i = t; i < BKT_NODES; i += 256) sc2[i] = degc[i];
    __syncthreads();
    // Hillis-Steele inclusive scan over 512 with 256 threads
    for (int o = 1; o < BKT_NODES; o <<= 1){
        int i0 = t, i1 = t + 256;
        int a0 = (i0 >= o) ? sc2[i0 - o] : 0;
        int a1 = (i1 >= o) ? sc2[i1 - o] : 0;
        __syncthreads();
        sc2[i0] += a0; sc2[i1] += a1;
        __syncthreads();
    }
    for (int i = t; i < BKT_NODES; i += 256){
        int cur = p0 + sc2[i] - degc[i];           // global exclusive offset
        if (i < nmax) off[node0 + i] = cur;
        degc[i] = cur;                              // becomes global cursor
    }
    __syncthreads();
    for (int i = t; i < m; i += 256){
        unsigned long long pr = pairs[p0 + i];
        int d = (int)(pr >> 32) - node0;
        int pos = atomicAdd(&degc[d], 1);
        csr_src[pos] = (int)(unsigned)pr;          // random only within 32KB window
    }
}

// ---------------- W1 split (fp32 -> bf16 hi/lo), transpose + XOR-swizzle ----------------

__global__ void __launch_bounds__(256) k_splitW(const float* __restrict__ W1,
                                                short* __restrict__ WTH, short* __restrict__ WTL){
    int i = blockIdx.x * 256 + threadIdx.x;   // 32768 elems
    if (i >= F_IN * HD1) return;
    int k = i >> 7, n = i & 127;
    float v = W1[i];
    unsigned u = __float_as_uint(v);
    short hs = (short)(u >> 16);
    float lo = v - __uint_as_float(u & 0xffff0000u);
    short ls = (short)(__float_as_uint(lo) >> 16);
    int idx = n * 256 + (k ^ ((n & 7) << 3));
    WTH[idx] = hs;
    WTL[idx] = ls;
}

// ---------------- GEMM1 (MFMA bf16x2): h1f8 = fp8(feat @ W1) ----------------

__device__ __forceinline__ void split8(float4 f0, float4 f1, short8& h, short8& l){
    float f[8] = {f0.x, f0.y, f0.z, f0.w, f1.x, f1.y, f1.z, f1.w};
    #pragma unroll
    for (int i = 0; i < 8; i++){
        unsigned u = __float_as_uint(f[i]);
        h[i] = (short)(u >> 16);
        float lo = f[i] - __uint_as_float(u & 0xffff0000u);
        l[i] = (short)(__float_as_uint(lo) >> 16);
    }
}

__global__ void __launch_bounds__(256, 2) k_gemm1m(const float* __restrict__ feat,
                                                   const short* __restrict__ WTH, const short* __restrict__ WTL,
                                                   unsigned char* __restrict__ h1f8){
    __shared__ short sWH[64 * 256];
    __shared__ short sWL[64 * 256];
    int t = threadIdx.x;
    int ch = blockIdx.y;
    {
        const short8* gh = (const short8*)(WTH + (size_t)ch * 16384);
        const short8* gl = (const short8*)(WTL + (size_t)ch * 16384);
        short8* sh = (short8*)sWH;
        short8* sl = (short8*)sWL;
        for (int i = t; i < 2048; i += 256){ sh[i] = gh[i]; sl[i] = gl[i]; }
    }
    __syncthreads();

    int wid = t >> 6, lane = t & 63;
    int m16 = lane & 15, kg = lane >> 4;
    int rowb = blockIdx.x * 128 + wid * 32;

    f32x4 acc[2][4];
    #pragma unroll
    for (int a = 0; a < 2; a++)
        #pragma unroll
        for (int b = 0; b < 4; b++)
            acc[a][b] = (f32x4){0.f, 0.f, 0.f, 0.f};

    int r0 = rowb + m16;       if (r0 > N_NODES - 1) r0 = N_NODES - 1;
    int r1 = rowb + 16 + m16;  if (r1 > N_NODES - 1) r1 = N_NODES - 1;
    const float* fp0 = feat + (size_t)r0 * F_IN;
    const float* fp1 = feat + (size_t)r1 * F_IN;

    #pragma unroll
    for (int ks = 0; ks < 8; ks++){
        int kbase = ks * 32 + kg * 8;
        short8 ah[2], al[2];
        {
            const float4* p = (const float4*)(fp0 + kbase);
            split8(p[0], p[1], ah[0], al[0]);
        }
        {
            const float4* p = (const float4*)(fp1 + kbase);
            split8(p[0], p[1], ah[1], al[1]);
        }
        bf16x8 AH0 = __builtin_bit_cast(bf16x8, ah[0]);
        bf16x8 AH1 = __builtin_bit_cast(bf16x8, ah[1]);
        bf16x8 AL0 = __builtin_bit_cast(bf16x8, al[0]);
        bf16x8 AL1 = __builtin_bit_cast(bf16x8, al[1]);
        #pragma unroll
        for (int c = 0; c < 4; c++){
            int n = (c << 4) + m16;
            int kk = kbase ^ ((n & 7) << 3);
            bf16x8 bh = __builtin_bit_cast(bf16x8, *(const short8*)(sWH + n * 256 + kk));
            bf16x8 bl = __builtin_bit_cast(bf16x8, *(const short8*)(sWL + n * 256 + kk));
            acc[0][c] = __builtin_amdgcn_mfma_f32_16x16x32_bf16(AH0, bh, acc[0][c], 0, 0, 0);
            acc[1][c] = __builtin_amdgcn_mfma_f32_16x16x32_bf16(AH1, bh, acc[1][c], 0, 0, 0);
            acc[0][c] = __builtin_amdgcn_mfma_f32_16x16x32_bf16(AH0, bl, acc[0][c], 0, 0, 0);
            acc[1][c] = __builtin_amdgcn_mfma_f32_16x16x32_bf16(AH1, bl, acc[1][c], 0, 0, 0);
            acc[0][c] = __builtin_amdgcn_mfma_f32_16x16x32_bf16(AL0, bh, acc[0][c], 0, 0, 0);
            acc[1][c] = __builtin_amdgcn_mfma_f32_16x16x32_bf16(AL1, bh, acc[1][c], 0, 0, 0);
        }
    }

    #pragma unroll
    for (int rf = 0; rf < 2; rf++){
        #pragma unroll
        for (int c = 0; c < 4; c++){
            #pragma unroll
            for (int r = 0; r < 4; r++){
                int row = rowb + rf * 16 + kg * 4 + r;
                if (row < N_NODES){
                    int col = ch * 64 + c * 16 + m16;
                    h1f8[(size_t)row * HD1 + col] = f2fp8(acc[rf][c][r]);
                }
            }
        }
    }
}

// ---------------- el1/er1 from h1f8 (el1 stored bf16, er1 fp32) ----------------

__global__ void __launch_bounds__(256) k_attn1(const unsigned char* __restrict__ h1f8,
                                               const float* __restrict__ al1, const float* __restrict__ ar1,
                                               unsigned short* __restrict__ el1b, float* __restrict__ er1){
    int i = blockIdx.x * 256 + threadIdx.x;
    if (i >= N_NODES * HEADS) return;
    int n = i >> 3, h = i & 7;
    const unsigned* hp = (const unsigned*)(h1f8 + (size_t)n * HD1 + h * HID);
    float pe = 0.f, pr = 0.f;
    #pragma unroll
    for (int j = 0; j < 4; j++){
        unsigned u = hp[j];
        float x0 = __builtin_amdgcn_cvt_f32_fp8(u, 0);
        float x1 = __builtin_amdgcn_cvt_f32_fp8(u, 1);
        float x2 = __builtin_amdgcn_cvt_f32_fp8(u, 2);
        float x3 = __builtin_amdgcn_cvt_f32_fp8(u, 3);
        const float4 a = ((const float4*)(al1 + h * HID))[j];
        const float4 r = ((const float4*)(ar1 + h * HID))[j];
        pe += x0 * a.x + x1 * a.y + x2 * a.z + x3 * a.w;
        pr += x0 * r.x + x1 * r.y + x2 * r.z + x3 * r.w;
    }
    el1b[i] = f2bf(pe);
    er1[i] = pr;
}

// ---------------- Layer-1 aggregation: one wave per dst node, 2 edges/iter, fp8 payload ----------------

__global__ void __launch_bounds__(256) k_agg1(const int* __restrict__ off, const int* __restrict__ csr_src,
                                              const unsigned short* __restrict__ el1b,
                                              const float* __restrict__ er1,
                                              const unsigned char* __restrict__ h1f8,
                                              const float* __restrict__ b1,
                                              unsigned short* __restrict__ x2b){
    int wid = threadIdx.x >> 6, lane = threadIdx.x & 63;
    int n = blockIdx.x * 4 + wid;
    if (n >= N_NODES) return;
    int jb = off[n], je = off[n + 1];
    int q = lane & 31;
    int half = lane >> 5;
    int hh = q >> 2;                       // head for my 4 columns
    float ern = er1[n * HEADS + hh];
    float acc0 = 0.f, acc1 = 0.f, acc2 = 0.f, acc3 = 0.f, wsum = 0.f;

    #pragma unroll 2
    for (int j = jb; j < je; j += 2){
        int j1 = (j + 1 < je) ? j + 1 : j;
        int jj = half ? j1 : j;
        int s = csr_src[jj];
        float el = bf2f(el1b[(size_t)s * HEADS + hh]);
        float wv = __expf(leaky(el + ern));
        if (half && (j + 1 >= je)) wv = 0.f;
        unsigned u = *(const unsigned*)(h1f8 + (size_t)s * HD1 + q * 4);
        float v0 = __builtin_amdgcn_cvt_f32_fp8(u, 0);
        float v1 = __builtin_amdgcn_cvt_f32_fp8(u, 1);
        float v2 = __builtin_amdgcn_cvt_f32_fp8(u, 2);
        float v3 = __builtin_amdgcn_cvt_f32_fp8(u, 3);
        acc0 += wv * v0;
        acc1 += wv * v1;
        acc2 += wv * v2;
        acc3 += wv * v3;
        wsum += wv;
    }

    // combine halves
    acc0 += __shfl_xor(acc0, 32);
    acc1 += __shfl_xor(acc1, 32);
    acc2 += __shfl_xor(acc2, 32);
    acc3 += __shfl_xor(acc3, 32);
    wsum += __shfl_xor(wsum, 32);

    if (half == 0){
        float inv = (je > jb) ? 1.f / wsum : 0.f;
        float o0 = acc0 * inv, o1 = acc1 * inv, o2 = acc2 * inv, o3 = acc3 * inv;
        float4 bv = *(const float4*)(b1 + q * 4);
        o0 += bv.x; o1 += bv.y; o2 += bv.z; o3 += bv.w;
        o0 = o0 > 0.f ? o0 : __expf(o0) - 1.f;
        o1 = o1 > 0.f ? o1 : __expf(o1) - 1.f;
        o2 = o2 > 0.f ? o2 : __expf(o2) - 1.f;
        o3 = o3 > 0.f ? o3 : __expf(o3) - 1.f;
        ushort4 ov = { f2bf(o0), f2bf(o1), f2bf(o2), f2bf(o3) };
        *(ushort4*)(x2b + (size_t)n * HD1 + q * 4) = ov;
    }
}

// ---------------- GEMM2: h2b = bf16(x2 @ W2), fused el2/er2 ----------------

__global__ void __launch_bounds__(256) k_gemm2(const unsigned short* __restrict__ x2b, const float* __restrict__ W2,
                                               const float* __restrict__ al2, const float* __restrict__ ar2,
                                               unsigned short* __restrict__ h2b, float* __restrict__ el2, float* __restrict__ er2){
    __shared__ float sW[HD1 * NC];   // 8 KB
    __shared__ float sX[16 * HD1];   // 8 KB
    int t = threadIdx.x;
    for (int i = t; i < (HD1 * NC) / 4; i += 256)
        ((float4*)sW)[i] = ((const float4*)W2)[i];
    int r = t >> 4, c = t & 15;
    float a2 = al2[c], r2 = ar2[c];
    for (int g = blockIdx.x; g * 16 < N_NODES; g += gridDim.x){
        int rowb = g * 16;
        __syncthreads();
        {
            ushort4 v = ((const ushort4*)(x2b + (size_t)rowb * HD1))[t * 2];
            ushort4 v2 = ((const ushort4*)(x2b + (size_t)rowb * HD1))[t * 2 + 1];
            float4 f0 = { bf2f(v.x), bf2f(v.y), bf2f(v.z), bf2f(v.w) };
            float4 f1 = { bf2f(v2.x), bf2f(v2.y), bf2f(v2.z), bf2f(v2.w) };
            ((float4*)sX)[t * 2] = f0;
            ((float4*)sX)[t * 2 + 1] = f1;
        }
        __syncthreads();
        float acc = 0.f;
        #pragma unroll 8
        for (int k = 0; k < HD1; k++)
            acc += sX[r * HD1 + k] * sW[k * NC + c];
        int row = rowb + r;
        h2b[row * NC + c] = f2bf(acc);
        float pe = acc * a2, pr = acc * r2;
        #pragma unroll
        for (int d = 1; d < 16; d <<= 1){ pe += __shfl_xor(pe, d); pr += __shfl_xor(pr, d); }
        if (c == 0){ el2[row] = pe; er2[row] = pr; }
    }
}

// ---------------- Layer-2 aggregation + bias + log_softmax ----------------

__global__ void __launch_bounds__(256) k_agg2(const int* __restrict__ off, const int* __restrict__ csr_src,
                                              const float* __restrict__ el2, const float* __restrict__ er2,
                                              const unsigned short* __restrict__ h2b, const float* __restrict__ b2,
                                              float* __restrict__ out){
    int t = threadIdx.x;
    int sub = t >> 4;          // 16 nodes per block
    int c = t & 15;
    int n = blockIdx.x * 16 + sub;
    if (n >= N_NODES) return;
    int jb = off[n], je = off[n + 1];
    float er = er2[n];
    float accA = 0.f, accB = 0.f, wsA = 0.f, wsB = 0.f;
    int j = jb;
    for (; j + 1 < je; j += 2){
        int s0 = csr_src[j];
        int s1 = csr_src[j + 1];
        float w0 = __expf(leaky(el2[s0] + er));
        float w1 = __expf(leaky(el2[s1] + er));
        float v0 = bf2f(h2b[(size_t)s0 * NC + c]);
        float v1 = bf2f(h2b[(size_t)s1 * NC + c]);
        wsA += w0; accA += w0 * v0;
        wsB += w1; accB += w1 * v1;
    }
    if (j < je){
        int s0 = csr_src[j];
        float w0 = __expf(leaky(el2[s0] + er));
        wsA += w0; accA += w0 * bf2f(h2b[(size_t)s0 * NC + c]);
    }
    float acc = accA + accB, wsum = wsA + wsB;
    float o = (je > jb) ? acc / wsum : 0.f;
    o += b2[c];
    // log_softmax over the 16 classes (16-lane group)
    float m = o;
    #pragma unroll
    for (int d = 1; d < 16; d <<= 1) m = fmaxf(m, __shfl_xor(m, d));
    float ex = __expf(o - m);
    #pragma unroll
    for (int d = 1; d < 16; d <<= 1) ex += __shfl_xor(ex, d);
    out[(size_t)n * NC + c] = o - m - __logf(ex);
}

// ---------------- launch ----------------

extern "C" void kernel_launch(void* const* d_in, const int* in_sizes, int n_in,
                              void* d_out, int out_size, void* d_ws, size_t ws_size,
                              hipStream_t stream){
    const float* feat = (const float*)d_in[0];
    const int*   src  = (const int*)d_in[1];
    const int*   dst  = (const int*)d_in[2];
    const float* W1   = (const float*)d_in[3];
    const float* al1  = (const float*)d_in[4];
    const float* ar1  = (const float*)d_in[5];
    const float* b1   = (const float*)d_in[6];
    const float* W2   = (const float*)d_in[7];
    const float* al2  = (const float*)d_in[8];
    const float* ar2  = (const float*)d_in[9];
    const float* b2   = (const float*)d_in[10];
    float* out = (float*)d_out;

    char* w = (char*)d_ws;
    auto alloc = [&](size_t bytes) -> char* {
        char* p = w;
        w += (bytes + 255) & ~(size_t)255;
        return p;
    };
    int*   off      = (int*)alloc((size_t)(N_NODES + 1) * 4);
    int*   csr_src  = (int*)alloc((size_t)N_EDGES * 4);
    unsigned long long* pairs = (unsigned long long*)alloc((size_t)N_EDGES * 8);
    int*   bucketTotal  = (int*)alloc((size_t)(NBKT + 1) * 4);
    int*   bucketBase   = (int*)alloc((size_t)(NBKT + 1) * 4);
    int*   bucketCursor = (int*)alloc((size_t)(NBKT + 1) * 4);
    unsigned char*  h1f8 = (unsigned char*)alloc((size_t)N_NODES * HD1);
    unsigned short* el1b = (unsigned short*)alloc((size_t)N_NODES * HEADS * 2);
    float* er1v    = (float*)alloc((size_t)N_NODES * HEADS * 4);
    unsigned short* x2b = (unsigned short*)alloc((size_t)N_NODES * HD1 * 2);
    unsigned short* h2b = (unsigned short*)alloc((size_t)N_NODES * NC * 2);
    float* el2v    = (float*)alloc((size_t)N_NODES * 4);
    float* er2v    = (float*)alloc((size_t)N_NODES * 4);
    short* WTH     = (short*)alloc((size_t)F_IN * HD1 * 2);
    short* WTL     = (short*)alloc((size_t)F_IN * HD1 * 2);

    // CSR build (bucketed two-pass, no random global scatter)
    hipMemsetAsync(bucketTotal, 0, (size_t)(NBKT + 1) * 4, stream);
    k_p1hist<<<P1_BLOCKS, 256, 0, stream>>>(dst, bucketTotal);
    k_p1scan<<<1, 256, 0, stream>>>(bucketTotal, bucketBase, bucketCursor, off);
    k_p1bin<<<P1_BLOCKS, 256, 0, stream>>>(src, dst, bucketCursor, pairs);
    k_p2place<<<NBKT, 256, 0, stream>>>(pairs, bucketBase, off, csr_src);

    // Layer 1 compute
    k_splitW<<<(F_IN * HD1 + 255) / 256, 256, 0, stream>>>(W1, WTH, WTL);
    dim3 g1((N_NODES + 127) / 128, 2);
    k_gemm1m<<<g1, 256, 0, stream>>>(feat, WTH, WTL, h1f8);
    k_attn1<<<(N_NODES * HEADS + 255) / 256, 256, 0, stream>>>(h1f8, al1, ar1, el1b, er1v);

    // Layer-1 aggregation
    k_agg1<<<(N_NODES + 3) / 4, 256, 0, stream>>>(off, csr_src, el1b, er1v, h1f8, b1, x2b);

    // Layer 2
    k_gemm2<<<1024, 256, 0, stream>>>(x2b, W2, al2, ar2, h2b, el2v, er2v);
    k_agg2<<<(N_NODES + 15) / 16, 256, 0, stream>>>(off, csr_src, el2v, er2v, h2b, b2, out);
}

// Round 7
// 247.804 us; speedup vs baseline: 1.6223x; 1.0443x over previous
//
#include <hip/hip_runtime.h>

#define N_NODES 100000
#define N_EDGES 1600000
#define F_IN 256
#define HD1 128   // HEADS*HID
#define HEADS 8
#define HID 16
#define NC 16
#define NEG_SLOPE 0.2f

// ---- bucketed CSR build params ----
#define BKT_NODES 512
#define NBKT ((N_NODES + BKT_NODES - 1) / BKT_NODES)   // 196
#define P1_EPB 8192
#define P1_BLOCKS ((N_EDGES + P1_EPB - 1) / P1_EPB)    // 196

__device__ __forceinline__ float leaky(float x){ return x > 0.f ? x : NEG_SLOPE * x; }
__device__ __forceinline__ unsigned short f2bf(float f){
    unsigned u = __float_as_uint(f);
    u += 0x7fff + ((u >> 16) & 1);       // round-to-nearest-even
    return (unsigned short)(u >> 16);
}
__device__ __forceinline__ float bf2f(unsigned short s){
    return __uint_as_float((unsigned)s << 16);
}
__device__ __forceinline__ unsigned char f2fp8(float v){
    return (unsigned char)(__builtin_amdgcn_cvt_pk_fp8_f32(v, v, 0, false) & 0xff);
}

typedef __bf16 bf16x8 __attribute__((ext_vector_type(8)));
typedef short short8 __attribute__((ext_vector_type(8)));
typedef float f32x4 __attribute__((ext_vector_type(4)));
typedef float f32x2 __attribute__((ext_vector_type(2)));
typedef unsigned short ushort8 __attribute__((ext_vector_type(8)));

// ---------------- CSR build: bucketed, no random global scatter ----------------

__global__ void __launch_bounds__(256) k_p1hist(const int* __restrict__ dst, int* __restrict__ bucketTotal){
    __shared__ int h[NBKT];
    int t = threadIdx.x;
    for (int i = t; i < NBKT; i += 256) h[i] = 0;
    __syncthreads();
    int base = blockIdx.x * P1_EPB;
    int m = min(P1_EPB, N_EDGES - base);
    for (int i = t; i < m; i += 256) atomicAdd(&h[(unsigned)dst[base + i] >> 9], 1);
    __syncthreads();
    for (int i = t; i < NBKT; i += 256) if (h[i]) atomicAdd(&bucketTotal[i], h[i]);
}

__global__ void __launch_bounds__(256) k_p1scan(const int* __restrict__ bucketTotal,
                                                int* __restrict__ bucketBase, int* __restrict__ bucketCursor,
                                                int* __restrict__ off){
    __shared__ int sc[256];
    int t = threadIdx.x;
    int v = (t < NBKT) ? bucketTotal[t] : 0;
    sc[t] = v; __syncthreads();
    for (int o = 1; o < 256; o <<= 1){
        int a = (t >= o) ? sc[t - o] : 0;
        __syncthreads();
        sc[t] += a;
        __syncthreads();
    }
    if (t < NBKT){
        int b = sc[t] - v;         // exclusive
        bucketBase[t] = b;
        bucketCursor[t] = b;
    }
    if (t == 0){ bucketBase[NBKT] = N_EDGES; off[N_NODES] = N_EDGES; }
}

__global__ void __launch_bounds__(256) k_p1bin(const int* __restrict__ src, const int* __restrict__ dst,
                                               int* __restrict__ bucketCursor,
                                               unsigned long long* __restrict__ pairs){
    __shared__ unsigned long long pl[P1_EPB];   // 64 KB
    __shared__ int h[NBKT];                     // hist -> running cursor
    __shared__ int dl[NBKT];                    // global-base minus local-base
    __shared__ int sc[256];
    int t = threadIdx.x;
    for (int i = t; i < NBKT; i += 256) h[i] = 0;
    __syncthreads();
    int base = blockIdx.x * P1_EPB;
    int m = min(P1_EPB, N_EDGES - base);
    for (int i = t; i < m; i += 256) atomicAdd(&h[(unsigned)dst[base + i] >> 9], 1);
    __syncthreads();
    int v = (t < NBKT) ? h[t] : 0;
    sc[t] = v; __syncthreads();
    for (int o = 1; o < 256; o <<= 1){
        int a = (t >= o) ? sc[t - o] : 0;
        __syncthreads();
        sc[t] += a;
        __syncthreads();
    }
    if (t < NBKT){
        int ex = sc[t] - v;                        // local exclusive base
        int gb = v ? atomicAdd(&bucketCursor[t], v) : 0;
        dl[t] = gb - ex;
        h[t] = ex;                                 // reuse as running local cursor
    }
    __syncthreads();
    for (int i = t; i < m; i += 256){
        int d = dst[base + i], s = src[base + i];
        int b = (unsigned)d >> 9;
        int p = atomicAdd(&h[b], 1);
        pl[p] = ((unsigned long long)(unsigned)d << 32) | (unsigned)s;
    }
    __syncthreads();
    for (int i = t; i < m; i += 256){
        unsigned long long pr = pl[i];
        int b = (unsigned)(pr >> 32) >> 9;
        pairs[i + dl[b]] = pr;                     // sequential-run writes
    }
}

__global__ void __launch_bounds__(256) k_p2place(const unsigned long long* __restrict__ pairs,
                                                 const int* __restrict__ bucketBase,
                                                 int* __restrict__ off, int* __restrict__ csr_src){
    __shared__ int degc[BKT_NODES];
    __shared__ int sc2[BKT_NODES];
    int t = threadIdx.x;
    int b = blockIdx.x;
    int node0 = b * BKT_NODES;
    int nmax = min(BKT_NODES, N_NODES - node0);
    int p0 = bucketBase[b], p1 = bucketBase[b + 1];
    int m = p1 - p0;
    for (int i = t; i < BKT_NODES; i += 256) degc[i] = 0;
    __syncthreads();
    for (int i = t; i < m; i += 256){
        int d = (int)(pairs[p0 + i] >> 32) - node0;
        atomicAdd(&degc[d], 1);
    }
    __syncthreads();
    for (int i = t; i < BKT_NODES; i += 256) sc2[i] = degc[i];
    __syncthreads();
    // Hillis-Steele inclusive scan over 512 with 256 threads
    for (int o = 1; o < BKT_NODES; o <<= 1){
        int i0 = t, i1 = t + 256;
        int a0 = (i0 >= o) ? sc2[i0 - o] : 0;
        int a1 = (i1 >= o) ? sc2[i1 - o] : 0;
        __syncthreads();
        sc2[i0] += a0; sc2[i1] += a1;
        __syncthreads();
    }
    for (int i = t; i < BKT_NODES; i += 256){
        int cur = p0 + sc2[i] - degc[i];           // global exclusive offset
        if (i < nmax) off[node0 + i] = cur;
        degc[i] = cur;                              // becomes global cursor
    }
    __syncthreads();
    for (int i = t; i < m; i += 256){
        unsigned long long pr = pairs[p0 + i];
        int d = (int)(pr >> 32) - node0;
        int pos = atomicAdd(&degc[d], 1);
        csr_src[pos] = (int)(unsigned)pr;          // random only within 32KB window
    }
}

// ---------------- W1 split (fp32 -> bf16 hi/lo), transpose + XOR-swizzle ----------------

__global__ void __launch_bounds__(256) k_splitW(const float* __restrict__ W1,
                                                short* __restrict__ WTH, short* __restrict__ WTL){
    int i = blockIdx.x * 256 + threadIdx.x;   // 32768 elems
    if (i >= F_IN * HD1) return;
    int k = i >> 7, n = i & 127;
    float v = W1[i];
    unsigned u = __float_as_uint(v);
    short hs = (short)(u >> 16);
    float lo = v - __uint_as_float(u & 0xffff0000u);
    short ls = (short)(__float_as_uint(lo) >> 16);
    int idx = n * 256 + (k ^ ((n & 7) << 3));
    WTH[idx] = hs;
    WTL[idx] = ls;
}

// ---------------- GEMM1 (MFMA bf16x2): h1f8 = fp8(feat @ W1) ----------------

__device__ __forceinline__ void split8(float4 f0, float4 f1, short8& h, short8& l){
    float f[8] = {f0.x, f0.y, f0.z, f0.w, f1.x, f1.y, f1.z, f1.w};
    #pragma unroll
    for (int i = 0; i < 8; i++){
        unsigned u = __float_as_uint(f[i]);
        h[i] = (short)(u >> 16);
        float lo = f[i] - __uint_as_float(u & 0xffff0000u);
        l[i] = (short)(__float_as_uint(lo) >> 16);
    }
}

__global__ void __launch_bounds__(256, 2) k_gemm1m(const float* __restrict__ feat,
                                                   const short* __restrict__ WTH, const short* __restrict__ WTL,
                                                   unsigned char* __restrict__ h1f8){
    __shared__ short sWH[64 * 256];
    __shared__ short sWL[64 * 256];
    int t = threadIdx.x;
    int ch = blockIdx.y;
    {
        const short8* gh = (const short8*)(WTH + (size_t)ch * 16384);
        const short8* gl = (const short8*)(WTL + (size_t)ch * 16384);
        short8* sh = (short8*)sWH;
        short8* sl = (short8*)sWL;
        for (int i = t; i < 2048; i += 256){ sh[i] = gh[i]; sl[i] = gl[i]; }
    }
    __syncthreads();

    int wid = t >> 6, lane = t & 63;
    int m16 = lane & 15, kg = lane >> 4;
    int rowb = blockIdx.x * 128 + wid * 32;

    f32x4 acc[2][4];
    #pragma unroll
    for (int a = 0; a < 2; a++)
        #pragma unroll
        for (int b = 0; b < 4; b++)
            acc[a][b] = (f32x4){0.f, 0.f, 0.f, 0.f};

    int r0 = rowb + m16;       if (r0 > N_NODES - 1) r0 = N_NODES - 1;
    int r1 = rowb + 16 + m16;  if (r1 > N_NODES - 1) r1 = N_NODES - 1;
    const float* fp0 = feat + (size_t)r0 * F_IN;
    const float* fp1 = feat + (size_t)r1 * F_IN;

    #pragma unroll
    for (int ks = 0; ks < 8; ks++){
        int kbase = ks * 32 + kg * 8;
        short8 ah[2], al[2];
        {
            const float4* p = (const float4*)(fp0 + kbase);
            split8(p[0], p[1], ah[0], al[0]);
        }
        {
            const float4* p = (const float4*)(fp1 + kbase);
            split8(p[0], p[1], ah[1], al[1]);
        }
        bf16x8 AH0 = __builtin_bit_cast(bf16x8, ah[0]);
        bf16x8 AH1 = __builtin_bit_cast(bf16x8, ah[1]);
        bf16x8 AL0 = __builtin_bit_cast(bf16x8, al[0]);
        bf16x8 AL1 = __builtin_bit_cast(bf16x8, al[1]);
        #pragma unroll
        for (int c = 0; c < 4; c++){
            int n = (c << 4) + m16;
            int kk = kbase ^ ((n & 7) << 3);
            bf16x8 bh = __builtin_bit_cast(bf16x8, *(const short8*)(sWH + n * 256 + kk));
            bf16x8 bl = __builtin_bit_cast(bf16x8, *(const short8*)(sWL + n * 256 + kk));
            acc[0][c] = __builtin_amdgcn_mfma_f32_16x16x32_bf16(AH0, bh, acc[0][c], 0, 0, 0);
            acc[1][c] = __builtin_amdgcn_mfma_f32_16x16x32_bf16(AH1, bh, acc[1][c], 0, 0, 0);
            acc[0][c] = __builtin_amdgcn_mfma_f32_16x16x32_bf16(AH0, bl, acc[0][c], 0, 0, 0);
            acc[1][c] = __builtin_amdgcn_mfma_f32_16x16x32_bf16(AH1, bl, acc[1][c], 0, 0, 0);
            acc[0][c] = __builtin_amdgcn_mfma_f32_16x16x32_bf16(AL0, bh, acc[0][c], 0, 0, 0);
            acc[1][c] = __builtin_amdgcn_mfma_f32_16x16x32_bf16(AL1, bh, acc[1][c], 0, 0, 0);
        }
    }

    #pragma unroll
    for (int rf = 0; rf < 2; rf++){
        #pragma unroll
        for (int c = 0; c < 4; c++){
            #pragma unroll
            for (int r = 0; r < 4; r++){
                int row = rowb + rf * 16 + kg * 4 + r;
                if (row < N_NODES){
                    int col = ch * 64 + c * 16 + m16;
                    h1f8[(size_t)row * HD1 + col] = f2fp8(acc[rf][c][r]);
                }
            }
        }
    }
}

// ---------------- el1/er1 from h1f8 (el1 stored bf16, er1 fp32) ----------------

__global__ void __launch_bounds__(256) k_attn1(const unsigned char* __restrict__ h1f8,
                                               const float* __restrict__ al1, const float* __restrict__ ar1,
                                               unsigned short* __restrict__ el1b, float* __restrict__ er1){
    int i = blockIdx.x * 256 + threadIdx.x;
    if (i >= N_NODES * HEADS) return;
    int n = i >> 3, h = i & 7;
    const unsigned* hp = (const unsigned*)(h1f8 + (size_t)n * HD1 + h * HID);
    float pe = 0.f, pr = 0.f;
    #pragma unroll
    for (int j = 0; j < 4; j++){
        unsigned u = hp[j];
        float x0 = __builtin_amdgcn_cvt_f32_fp8(u, 0);
        float x1 = __builtin_amdgcn_cvt_f32_fp8(u, 1);
        float x2 = __builtin_amdgcn_cvt_f32_fp8(u, 2);
        float x3 = __builtin_amdgcn_cvt_f32_fp8(u, 3);
        const float4 a = ((const float4*)(al1 + h * HID))[j];
        const float4 r = ((const float4*)(ar1 + h * HID))[j];
        pe += x0 * a.x + x1 * a.y + x2 * a.z + x3 * a.w;
        pr += x0 * r.x + x1 * r.y + x2 * r.z + x3 * r.w;
    }
    el1b[i] = f2bf(pe);
    er1[i] = pr;
}

// ---------------- Layer-1 aggregation: 1 wave/node, 16 lanes/edge, 4 edges/iter ----------------

__global__ void __launch_bounds__(256) k_agg1(const int* __restrict__ off, const int* __restrict__ csr_src,
                                              const unsigned short* __restrict__ el1b,
                                              const float* __restrict__ er1,
                                              const unsigned char* __restrict__ h1f8,
                                              const float* __restrict__ b1,
                                              unsigned short* __restrict__ x2b){
    int wid = threadIdx.x >> 6, lane = threadIdx.x & 63;
    int n = blockIdx.x * 4 + wid;
    if (n >= N_NODES) return;
    int jb = off[n], je = off[n + 1];
    int sub = lane >> 4;       // edge slot within quad (0..3)
    int q = lane & 15;         // column group: cols q*8 .. q*8+7
    int hh = q >> 1;           // head (2 lanes per head)
    float ern = er1[n * HEADS + hh];
    float a0=0.f,a1=0.f,a2=0.f,a3=0.f,a4=0.f,a5=0.f,a6=0.f,a7=0.f,wsum=0.f;

    #pragma unroll 2
    for (int j = jb; j < je; j += 4){
        int jj = j + sub;
        int jc = (jj < je) ? jj : je - 1;
        int s = csr_src[jc];
        float el = bf2f(el1b[s * HEADS + hh]);
        float wv = (jj < je) ? __expf(leaky(el + ern)) : 0.f;
        wsum += wv;
        uint2 u = *(const uint2*)(h1f8 + (((size_t)s) << 7) + (q << 3));
        f32x2 p0 = __builtin_amdgcn_cvt_pk_f32_fp8(u.x, 0);
        f32x2 p1 = __builtin_amdgcn_cvt_pk_f32_fp8(u.x, 1);
        f32x2 p2 = __builtin_amdgcn_cvt_pk_f32_fp8(u.y, 0);
        f32x2 p3 = __builtin_amdgcn_cvt_pk_f32_fp8(u.y, 1);
        a0 += wv * p0.x; a1 += wv * p0.y;
        a2 += wv * p1.x; a3 += wv * p1.y;
        a4 += wv * p2.x; a5 += wv * p2.y;
        a6 += wv * p3.x; a7 += wv * p3.y;
    }

    // reduce across the 4 edge-slots (lanes differing in bits 4,5)
    a0 += __shfl_xor(a0, 16); a0 += __shfl_xor(a0, 32);
    a1 += __shfl_xor(a1, 16); a1 += __shfl_xor(a1, 32);
    a2 += __shfl_xor(a2, 16); a2 += __shfl_xor(a2, 32);
    a3 += __shfl_xor(a3, 16); a3 += __shfl_xor(a3, 32);
    a4 += __shfl_xor(a4, 16); a4 += __shfl_xor(a4, 32);
    a5 += __shfl_xor(a5, 16); a5 += __shfl_xor(a5, 32);
    a6 += __shfl_xor(a6, 16); a6 += __shfl_xor(a6, 32);
    a7 += __shfl_xor(a7, 16); a7 += __shfl_xor(a7, 32);
    wsum += __shfl_xor(wsum, 16); wsum += __shfl_xor(wsum, 32);

    if (sub == 0){
        float inv = (je > jb) ? 1.f / wsum : 0.f;
        float o0 = a0*inv, o1 = a1*inv, o2 = a2*inv, o3 = a3*inv;
        float o4 = a4*inv, o5 = a5*inv, o6 = a6*inv, o7 = a7*inv;
        float4 bv0 = *(const float4*)(b1 + (q << 3));
        float4 bv1 = *(const float4*)(b1 + (q << 3) + 4);
        o0 += bv0.x; o1 += bv0.y; o2 += bv0.z; o3 += bv0.w;
        o4 += bv1.x; o5 += bv1.y; o6 += bv1.z; o7 += bv1.w;
        o0 = o0 > 0.f ? o0 : __expf(o0) - 1.f;
        o1 = o1 > 0.f ? o1 : __expf(o1) - 1.f;
        o2 = o2 > 0.f ? o2 : __expf(o2) - 1.f;
        o3 = o3 > 0.f ? o3 : __expf(o3) - 1.f;
        o4 = o4 > 0.f ? o4 : __expf(o4) - 1.f;
        o5 = o5 > 0.f ? o5 : __expf(o5) - 1.f;
        o6 = o6 > 0.f ? o6 : __expf(o6) - 1.f;
        o7 = o7 > 0.f ? o7 : __expf(o7) - 1.f;
        ushort8 ov = { f2bf(o0), f2bf(o1), f2bf(o2), f2bf(o3),
                       f2bf(o4), f2bf(o5), f2bf(o6), f2bf(o7) };
        *(ushort8*)(x2b + (size_t)n * HD1 + (q << 3)) = ov;
    }
}

// ---------------- GEMM2: h2b = bf16(x2 @ W2), fused el2/er2 ----------------

__global__ void __launch_bounds__(256) k_gemm2(const unsigned short* __restrict__ x2b, const float* __restrict__ W2,
                                               const float* __restrict__ al2, const float* __restrict__ ar2,
                                               unsigned short* __restrict__ h2b, float* __restrict__ el2, float* __restrict__ er2){
    __shared__ float sW[HD1 * NC];   // 8 KB
    __shared__ float sX[16 * HD1];   // 8 KB
    int t = threadIdx.x;
    for (int i = t; i < (HD1 * NC) / 4; i += 256)
        ((float4*)sW)[i] = ((const float4*)W2)[i];
    int r = t >> 4, c = t & 15;
    float a2 = al2[c], r2 = ar2[c];
    for (int g = blockIdx.x; g * 16 < N_NODES; g += gridDim.x){
        int rowb = g * 16;
        __syncthreads();
        {
            ushort4 v = ((const ushort4*)(x2b + (size_t)rowb * HD1))[t * 2];
            ushort4 v2 = ((const ushort4*)(x2b + (size_t)rowb * HD1))[t * 2 + 1];
            float4 f0 = { bf2f(v.x), bf2f(v.y), bf2f(v.z), bf2f(v.w) };
            float4 f1 = { bf2f(v2.x), bf2f(v2.y), bf2f(v2.z), bf2f(v2.w) };
            ((float4*)sX)[t * 2] = f0;
            ((float4*)sX)[t * 2 + 1] = f1;
        }
        __syncthreads();
        float acc = 0.f;
        #pragma unroll 8
        for (int k = 0; k < HD1; k++)
            acc += sX[r * HD1 + k] * sW[k * NC + c];
        int row = rowb + r;
        h2b[row * NC + c] = f2bf(acc);
        float pe = acc * a2, pr = acc * r2;
        #pragma unroll
        for (int d = 1; d < 16; d <<= 1){ pe += __shfl_xor(pe, d); pr += __shfl_xor(pr, d); }
        if (c == 0){ el2[row] = pe; er2[row] = pr; }
    }
}

// ---------------- Layer-2 aggregation + bias + log_softmax ----------------

__global__ void __launch_bounds__(256) k_agg2(const int* __restrict__ off, const int* __restrict__ csr_src,
                                              const float* __restrict__ el2, const float* __restrict__ er2,
                                              const unsigned short* __restrict__ h2b, const float* __restrict__ b2,
                                              float* __restrict__ out){
    int t = threadIdx.x;
    int sub = t >> 4;          // 16 nodes per block
    int c = t & 15;
    int n = blockIdx.x * 16 + sub;
    if (n >= N_NODES) return;
    int jb = off[n], je = off[n + 1];
    float er = er2[n];
    float accA = 0.f, accB = 0.f, wsA = 0.f, wsB = 0.f;
    int j = jb;
    for (; j + 1 < je; j += 2){
        int s0 = csr_src[j];
        int s1 = csr_src[j + 1];
        float w0 = __expf(leaky(el2[s0] + er));
        float w1 = __expf(leaky(el2[s1] + er));
        float v0 = bf2f(h2b[(size_t)s0 * NC + c]);
        float v1 = bf2f(h2b[(size_t)s1 * NC + c]);
        wsA += w0; accA += w0 * v0;
        wsB += w1; accB += w1 * v1;
    }
    if (j < je){
        int s0 = csr_src[j];
        float w0 = __expf(leaky(el2[s0] + er));
        wsA += w0; accA += w0 * bf2f(h2b[(size_t)s0 * NC + c]);
    }
    float acc = accA + accB, wsum = wsA + wsB;
    float o = (je > jb) ? acc / wsum : 0.f;
    o += b2[c];
    // log_softmax over the 16 classes (16-lane group)
    float m = o;
    #pragma unroll
    for (int d = 1; d < 16; d <<= 1) m = fmaxf(m, __shfl_xor(m, d));
    float ex = __expf(o - m);
    #pragma unroll
    for (int d = 1; d < 16; d <<= 1) ex += __shfl_xor(ex, d);
    out[(size_t)n * NC + c] = o - m - __logf(ex);
}

// ---------------- launch ----------------

extern "C" void kernel_launch(void* const* d_in, const int* in_sizes, int n_in,
                              void* d_out, int out_size, void* d_ws, size_t ws_size,
                              hipStream_t stream){
    const float* feat = (const float*)d_in[0];
    const int*   src  = (const int*)d_in[1];
    const int*   dst  = (const int*)d_in[2];
    const float* W1   = (const float*)d_in[3];
    const float* al1  = (const float*)d_in[4];
    const float* ar1  = (const float*)d_in[5];
    const float* b1   = (const float*)d_in[6];
    const float* W2   = (const float*)d_in[7];
    const float* al2  = (const float*)d_in[8];
    const float* ar2  = (const float*)d_in[9];
    const float* b2   = (const float*)d_in[10];
    float* out = (float*)d_out;

    char* w = (char*)d_ws;
    auto alloc = [&](size_t bytes) -> char* {
        char* p = w;
        w += (bytes + 255) & ~(size_t)255;
        return p;
    };
    int*   off      = (int*)alloc((size_t)(N_NODES + 1) * 4);
    int*   csr_src  = (int*)alloc((size_t)N_EDGES * 4);
    unsigned long long* pairs = (unsigned long long*)alloc((size_t)N_EDGES * 8);
    int*   bucketTotal  = (int*)alloc((size_t)(NBKT + 1) * 4);
    int*   bucketBase   = (int*)alloc((size_t)(NBKT + 1) * 4);
    int*   bucketCursor = (int*)alloc((size_t)(NBKT + 1) * 4);
    unsigned char*  h1f8 = (unsigned char*)alloc((size_t)N_NODES * HD1);
    unsigned short* el1b = (unsigned short*)alloc((size_t)N_NODES * HEADS * 2);
    float* er1v    = (float*)alloc((size_t)N_NODES * HEADS * 4);
    unsigned short* x2b = (unsigned short*)alloc((size_t)N_NODES * HD1 * 2);
    unsigned short* h2b = (unsigned short*)alloc((size_t)N_NODES * NC * 2);
    float* el2v    = (float*)alloc((size_t)N_NODES * 4);
    float* er2v    = (float*)alloc((size_t)N_NODES * 4);
    short* WTH     = (short*)alloc((size_t)F_IN * HD1 * 2);
    short* WTL     = (short*)alloc((size_t)F_IN * HD1 * 2);

    // CSR build (bucketed two-pass, no random global scatter)
    hipMemsetAsync(bucketTotal, 0, (size_t)(NBKT + 1) * 4, stream);
    k_p1hist<<<P1_BLOCKS, 256, 0, stream>>>(dst, bucketTotal);
    k_p1scan<<<1, 256, 0, stream>>>(bucketTotal, bucketBase, bucketCursor, off);
    k_p1bin<<<P1_BLOCKS, 256, 0, stream>>>(src, dst, bucketCursor, pairs);
    k_p2place<<<NBKT, 256, 0, stream>>>(pairs, bucketBase, off, csr_src);

    // Layer 1 compute
    k_splitW<<<(F_IN * HD1 + 255) / 256, 256, 0, stream>>>(W1, WTH, WTL);
    dim3 g1((N_NODES + 127) / 128, 2);
    k_gemm1m<<<g1, 256, 0, stream>>>(feat, WTH, WTL, h1f8);
    k_attn1<<<(N_NODES * HEADS + 255) / 256, 256, 0, stream>>>(h1f8, al1, ar1, el1b, er1v);

    // Layer-1 aggregation
    k_agg1<<<(N_NODES + 3) / 4, 256, 0, stream>>>(off, csr_src, el1b, er1v, h1f8, b1, x2b);

    // Layer 2
    k_gemm2<<<1024, 256, 0, stream>>>(x2b, W2, al2, ar2, h2b, el2v, er2v);
    k_agg2<<<(N_NODES + 15) / 16, 256, 0, stream>>>(off, csr_src, el2v, er2v, h2b, b2, out);
}

// Round 9
// 240.615 us; speedup vs baseline: 1.6707x; 1.0299x over previous
//
#include <hip/hip_runtime.h>

#define N_NODES 100000
#define N_EDGES 1600000
#define F_IN 256
#define HD1 128   // HEADS*HID
#define HEADS 8
#define HID 16
#define NC 16
#define NEG_SLOPE 0.2f

// ---- bucketed CSR build params ----
#define BKT_NODES 512
#define NBKT ((N_NODES + BKT_NODES - 1) / BKT_NODES)   // 196
#define P1_EPB 8192
#define P1_BLOCKS ((N_EDGES + P1_EPB - 1) / P1_EPB)    // 196

__device__ __forceinline__ float leaky(float x){ return x > 0.f ? x : NEG_SLOPE * x; }
__device__ __forceinline__ unsigned short f2bf(float f){
    unsigned u = __float_as_uint(f);
    u += 0x7fff + ((u >> 16) & 1);       // round-to-nearest-even
    return (unsigned short)(u >> 16);
}
__device__ __forceinline__ float bf2f(unsigned short s){
    return __uint_as_float((unsigned)s << 16);
}
__device__ __forceinline__ unsigned char f2fp8(float v){
    return (unsigned char)(__builtin_amdgcn_cvt_pk_fp8_f32(v, v, 0, false) & 0xff);
}

typedef __bf16 bf16x8 __attribute__((ext_vector_type(8)));
typedef short short8 __attribute__((ext_vector_type(8)));
typedef float f32x4 __attribute__((ext_vector_type(4)));
typedef float f32x2 __attribute__((ext_vector_type(2)));
typedef unsigned short ushort8 __attribute__((ext_vector_type(8)));

// ---------------- CSR build: bucketed, no random global scatter ----------------

__global__ void __launch_bounds__(256) k_p1hist(const int* __restrict__ dst, int* __restrict__ bucketTotal){
    __shared__ int h[NBKT];
    int t = threadIdx.x;
    for (int i = t; i < NBKT; i += 256) h[i] = 0;
    __syncthreads();
    int base = blockIdx.x * P1_EPB;
    int m = min(P1_EPB, N_EDGES - base);
    for (int i = t; i < m; i += 256) atomicAdd(&h[(unsigned)dst[base + i] >> 9], 1);
    __syncthreads();
    for (int i = t; i < NBKT; i += 256) if (h[i]) atomicAdd(&bucketTotal[i], h[i]);
}

__global__ void __launch_bounds__(256) k_p1scan(const int* __restrict__ bucketTotal,
                                                int* __restrict__ bucketBase, int* __restrict__ bucketCursor,
                                                int* __restrict__ off){
    __shared__ int sc[256];
    int t = threadIdx.x;
    int v = (t < NBKT) ? bucketTotal[t] : 0;
    sc[t] = v; __syncthreads();
    for (int o = 1; o < 256; o <<= 1){
        int a = (t >= o) ? sc[t - o] : 0;
        __syncthreads();
        sc[t] += a;
        __syncthreads();
    }
    if (t < NBKT){
        int b = sc[t] - v;         // exclusive
        bucketBase[t] = b;
        bucketCursor[t] = b;
    }
    if (t == 0){ bucketBase[NBKT] = N_EDGES; off[N_NODES] = N_EDGES; }
}

__global__ void __launch_bounds__(256) k_p1bin(const int* __restrict__ src, const int* __restrict__ dst,
                                               int* __restrict__ bucketCursor,
                                               unsigned long long* __restrict__ pairs){
    __shared__ unsigned long long pl[P1_EPB];   // 64 KB
    __shared__ int h[NBKT];                     // hist -> running cursor
    __shared__ int dl[NBKT];                    // global-base minus local-base
    __shared__ int sc[256];
    int t = threadIdx.x;
    for (int i = t; i < NBKT; i += 256) h[i] = 0;
    __syncthreads();
    int base = blockIdx.x * P1_EPB;
    int m = min(P1_EPB, N_EDGES - base);
    for (int i = t; i < m; i += 256) atomicAdd(&h[(unsigned)dst[base + i] >> 9], 1);
    __syncthreads();
    int v = (t < NBKT) ? h[t] : 0;
    sc[t] = v; __syncthreads();
    for (int o = 1; o < 256; o <<= 1){
        int a = (t >= o) ? sc[t - o] : 0;
        __syncthreads();
        sc[t] += a;
        __syncthreads();
    }
    if (t < NBKT){
        int ex = sc[t] - v;                        // local exclusive base
        int gb = v ? atomicAdd(&bucketCursor[t], v) : 0;
        dl[t] = gb - ex;
        h[t] = ex;                                 // reuse as running local cursor
    }
    __syncthreads();
    for (int i = t; i < m; i += 256){
        int d = dst[base + i], s = src[base + i];
        int b = (unsigned)d >> 9;
        int p = atomicAdd(&h[b], 1);
        pl[p] = ((unsigned long long)(unsigned)d << 32) | (unsigned)s;
    }
    __syncthreads();
    for (int i = t; i < m; i += 256){
        unsigned long long pr = pl[i];
        int b = (unsigned)(pr >> 32) >> 9;
        pairs[i + dl[b]] = pr;                     // sequential-run writes
    }
}

__global__ void __launch_bounds__(256) k_p2place(const unsigned long long* __restrict__ pairs,
                                                 const int* __restrict__ bucketBase,
                                                 int* __restrict__ off, int* __restrict__ csr_src){
    __shared__ int degc[BKT_NODES];
    __shared__ int sc2[BKT_NODES];
    int t = threadIdx.x;
    int b = blockIdx.x;
    int node0 = b * BKT_NODES;
    int nmax = min(BKT_NODES, N_NODES - node0);
    int p0 = bucketBase[b], p1 = bucketBase[b + 1];
    int m = p1 - p0;
    for (int i = t; i < BKT_NODES; i += 256) degc[i] = 0;
    __syncthreads();
    for (int i = t; i < m; i += 256){
        int d = (int)(pairs[p0 + i] >> 32) - node0;
        atomicAdd(&degc[d], 1);
    }
    __syncthreads();
    for (int i = t; i < BKT_NODES; i += 256) sc2[i] = degc[i];
    __syncthreads();
    // Hillis-Steele inclusive scan over 512 with 256 threads
    for (int o = 1; o < BKT_NODES; o <<= 1){
        int i0 = t, i1 = t + 256;
        int a0 = (i0 >= o) ? sc2[i0 - o] : 0;
        int a1 = (i1 >= o) ? sc2[i1 - o] : 0;
        __syncthreads();
        sc2[i0] += a0; sc2[i1] += a1;
        __syncthreads();
    }
    for (int i = t; i < BKT_NODES; i += 256){
        int cur = p0 + sc2[i] - degc[i];           // global exclusive offset
        if (i < nmax) off[node0 + i] = cur;
        degc[i] = cur;                              // becomes global cursor
    }
    __syncthreads();
    for (int i = t; i < m; i += 256){
        unsigned long long pr = pairs[p0 + i];
        int d = (int)(pr >> 32) - node0;
        int pos = atomicAdd(&degc[d], 1);
        csr_src[pos] = (int)(unsigned)pr;          // random only within 32KB window
    }
}

// ---------------- W1 -> bf16, transpose + XOR-swizzle ----------------

__global__ void __launch_bounds__(256) k_splitW(const float* __restrict__ W1,
                                                short* __restrict__ WTH){
    int i = blockIdx.x * 256 + threadIdx.x;   // 32768 elems
    if (i >= F_IN * HD1) return;
    int k = i >> 7, n = i & 127;
    int idx = n * 256 + (k ^ ((n & 7) << 3));
    WTH[idx] = (short)f2bf(W1[i]);
}

// ---------------- GEMM1 (MFMA bf16 single-term): h1f8 = fp8(feat @ W1) ----------------
// h1 is consumed exclusively as fp8 (~2% rms); single-term bf16 GEMM error (~0.3% rms)
// is negligible against that. 32KB LDS -> 4-5 blocks/CU for MLP.

__device__ __forceinline__ short8 pack8(float4 f0, float4 f1){
    float f[8] = {f0.x, f0.y, f0.z, f0.w, f1.x, f1.y, f1.z, f1.w};
    unsigned p[4];
    #pragma unroll
    for (int i = 0; i < 4; i++){
        unsigned u0 = __float_as_uint(f[2 * i]);
        unsigned u1 = __float_as_uint(f[2 * i + 1]);
        u0 += 0x7fff + ((u0 >> 16) & 1);
        u1 += 0x7fff + ((u1 >> 16) & 1);
        p[i] = (u0 >> 16) | (u1 & 0xffff0000u);
    }
    short8 r;
    r[0] = (short)(p[0] & 0xffff); r[1] = (short)(p[0] >> 16);
    r[2] = (short)(p[1] & 0xffff); r[3] = (short)(p[1] >> 16);
    r[4] = (short)(p[2] & 0xffff); r[5] = (short)(p[2] >> 16);
    r[6] = (short)(p[3] & 0xffff); r[7] = (short)(p[3] >> 16);
    return r;
}

__global__ void __launch_bounds__(256, 4) k_gemm1m(const float* __restrict__ feat,
                                                   const short* __restrict__ WTH,
                                                   unsigned char* __restrict__ h1f8){
    __shared__ short sWH[64 * 256];   // 32 KB
    int t = threadIdx.x;
    int ch = blockIdx.y;
    {
        const short8* gh = (const short8*)(WTH + (size_t)ch * 16384);
        short8* sh = (short8*)sWH;
        for (int i = t; i < 2048; i += 256) sh[i] = gh[i];
    }
    __syncthreads();

    int wid = t >> 6, lane = t & 63;
    int m16 = lane & 15, kg = lane >> 4;
    int rowb = blockIdx.x * 128 + wid * 32;

    f32x4 acc[2][4];
    #pragma unroll
    for (int a = 0; a < 2; a++)
        #pragma unroll
        for (int b = 0; b < 4; b++)
            acc[a][b] = (f32x4){0.f, 0.f, 0.f, 0.f};

    int r0 = rowb + m16;       if (r0 > N_NODES - 1) r0 = N_NODES - 1;
    int r1 = rowb + 16 + m16;  if (r1 > N_NODES - 1) r1 = N_NODES - 1;
    const float* fp0 = feat + (size_t)r0 * F_IN;
    const float* fp1 = feat + (size_t)r1 * F_IN;

    #pragma unroll
    for (int ks = 0; ks < 8; ks++){
        int kbase = ks * 32 + kg * 8;
        short8 a0, a1;
        {
            const float4* p = (const float4*)(fp0 + kbase);
            a0 = pack8(p[0], p[1]);
        }
        {
            const float4* p = (const float4*)(fp1 + kbase);
            a1 = pack8(p[0], p[1]);
        }
        bf16x8 AH0 = __builtin_bit_cast(bf16x8, a0);
        bf16x8 AH1 = __builtin_bit_cast(bf16x8, a1);
        #pragma unroll
        for (int c = 0; c < 4; c++){
            int n = (c << 4) + m16;
            int kk = kbase ^ ((n & 7) << 3);
            bf16x8 bh = __builtin_bit_cast(bf16x8, *(const short8*)(sWH + n * 256 + kk));
            acc[0][c] = __builtin_amdgcn_mfma_f32_16x16x32_bf16(AH0, bh, acc[0][c], 0, 0, 0);
            acc[1][c] = __builtin_amdgcn_mfma_f32_16x16x32_bf16(AH1, bh, acc[1][c], 0, 0, 0);
        }
    }

    #pragma unroll
    for (int rf = 0; rf < 2; rf++){
        #pragma unroll
        for (int c = 0; c < 4; c++){
            #pragma unroll
            for (int r = 0; r < 4; r++){
                int row = rowb + rf * 16 + kg * 4 + r;
                if (row < N_NODES){
                    int col = ch * 64 + c * 16 + m16;
                    h1f8[(size_t)row * HD1 + col] = f2fp8(acc[rf][c][r]);
                }
            }
        }
    }
}

// ---------------- el1/er1 from h1f8 (el1 stored bf16, er1 fp32) ----------------

__global__ void __launch_bounds__(256) k_attn1(const unsigned char* __restrict__ h1f8,
                                               const float* __restrict__ al1, const float* __restrict__ ar1,
                                               unsigned short* __restrict__ el1b, float* __restrict__ er1){
    int i = blockIdx.x * 256 + threadIdx.x;
    if (i >= N_NODES * HEADS) return;
    int n = i >> 3, h = i & 7;
    const unsigned* hp = (const unsigned*)(h1f8 + (size_t)n * HD1 + h * HID);
    float pe = 0.f, pr = 0.f;
    #pragma unroll
    for (int j = 0; j < 4; j++){
        unsigned u = hp[j];
        float x0 = __builtin_amdgcn_cvt_f32_fp8(u, 0);
        float x1 = __builtin_amdgcn_cvt_f32_fp8(u, 1);
        float x2 = __builtin_amdgcn_cvt_f32_fp8(u, 2);
        float x3 = __builtin_amdgcn_cvt_f32_fp8(u, 3);
        const float4 a = ((const float4*)(al1 + h * HID))[j];
        const float4 r = ((const float4*)(ar1 + h * HID))[j];
        pe += x0 * a.x + x1 * a.y + x2 * a.z + x3 * a.w;
        pr += x0 * r.x + x1 * r.y + x2 * r.z + x3 * r.w;
    }
    el1b[i] = f2bf(pe);
    er1[i] = pr;
}

// ---------------- Layer-1 aggregation: 1 wave/node, 16 lanes/edge, 4 edges/iter ----------------

__global__ void __launch_bounds__(256) k_agg1(const int* __restrict__ off, const int* __restrict__ csr_src,
                                              const unsigned short* __restrict__ el1b,
                                              const float* __restrict__ er1,
                                              const unsigned char* __restrict__ h1f8,
                                              const float* __restrict__ b1,
                                              unsigned short* __restrict__ x2b){
    int wid = threadIdx.x >> 6, lane = threadIdx.x & 63;
    int n = blockIdx.x * 4 + wid;
    if (n >= N_NODES) return;
    int jb = off[n], je = off[n + 1];
    int sub = lane >> 4;       // edge slot within quad (0..3)
    int q = lane & 15;         // column group: cols q*8 .. q*8+7
    int hh = q >> 1;           // head (2 lanes per head)
    float ern = er1[n * HEADS + hh];
    float a0=0.f,a1=0.f,a2=0.f,a3=0.f,a4=0.f,a5=0.f,a6=0.f,a7=0.f,wsum=0.f;

    #pragma unroll 2
    for (int j = jb; j < je; j += 4){
        int jj = j + sub;
        int jc = (jj < je) ? jj : je - 1;
        int s = csr_src[jc];
        float el = bf2f(el1b[s * HEADS + hh]);
        float wv = (jj < je) ? __expf(leaky(el + ern)) : 0.f;
        wsum += wv;
        uint2 u = *(const uint2*)(h1f8 + (((size_t)s) << 7) + (q << 3));
        f32x2 p0 = __builtin_amdgcn_cvt_pk_f32_fp8(u.x, 0);
        f32x2 p1 = __builtin_amdgcn_cvt_pk_f32_fp8(u.x, 1);
        f32x2 p2 = __builtin_amdgcn_cvt_pk_f32_fp8(u.y, 0);
        f32x2 p3 = __builtin_amdgcn_cvt_pk_f32_fp8(u.y, 1);
        a0 += wv * p0.x; a1 += wv * p0.y;
        a2 += wv * p1.x; a3 += wv * p1.y;
        a4 += wv * p2.x; a5 += wv * p2.y;
        a6 += wv * p3.x; a7 += wv * p3.y;
    }

    // reduce across the 4 edge-slots (lanes differing in bits 4,5)
    a0 += __shfl_xor(a0, 16); a0 += __shfl_xor(a0, 32);
    a1 += __shfl_xor(a1, 16); a1 += __shfl_xor(a1, 32);
    a2 += __shfl_xor(a2, 16); a2 += __shfl_xor(a2, 32);
    a3 += __shfl_xor(a3, 16); a3 += __shfl_xor(a3, 32);
    a4 += __shfl_xor(a4, 16); a4 += __shfl_xor(a4, 32);
    a5 += __shfl_xor(a5, 16); a5 += __shfl_xor(a5, 32);
    a6 += __shfl_xor(a6, 16); a6 += __shfl_xor(a6, 32);
    a7 += __shfl_xor(a7, 16); a7 += __shfl_xor(a7, 32);
    wsum += __shfl_xor(wsum, 16); wsum += __shfl_xor(wsum, 32);

    if (sub == 0){
        float inv = (je > jb) ? 1.f / wsum : 0.f;
        float o0 = a0*inv, o1 = a1*inv, o2 = a2*inv, o3 = a3*inv;
        float o4 = a4*inv, o5 = a5*inv, o6 = a6*inv, o7 = a7*inv;
        float4 bv0 = *(const float4*)(b1 + (q << 3));
        float4 bv1 = *(const float4*)(b1 + (q << 3) + 4);
        o0 += bv0.x; o1 += bv0.y; o2 += bv0.z; o3 += bv0.w;
        o4 += bv1.x; o5 += bv1.y; o6 += bv1.z; o7 += bv1.w;
        o0 = o0 > 0.f ? o0 : __expf(o0) - 1.f;
        o1 = o1 > 0.f ? o1 : __expf(o1) - 1.f;
        o2 = o2 > 0.f ? o2 : __expf(o2) - 1.f;
        o3 = o3 > 0.f ? o3 : __expf(o3) - 1.f;
        o4 = o4 > 0.f ? o4 : __expf(o4) - 1.f;
        o5 = o5 > 0.f ? o5 : __expf(o5) - 1.f;
        o6 = o6 > 0.f ? o6 : __expf(o6) - 1.f;
        o7 = o7 > 0.f ? o7 : __expf(o7) - 1.f;
        ushort8 ov = { f2bf(o0), f2bf(o1), f2bf(o2), f2bf(o3),
                       f2bf(o4), f2bf(o5), f2bf(o6), f2bf(o7) };
        *(ushort8*)(x2b + (size_t)n * HD1 + (q << 3)) = ov;
    }
}

// ---------------- GEMM2: h2b = bf16(x2 @ W2), fused el2/er2 ----------------

__global__ void __launch_bounds__(256) k_gemm2(const unsigned short* __restrict__ x2b, const float* __restrict__ W2,
                                               const float* __restrict__ al2, const float* __restrict__ ar2,
                                               unsigned short* __restrict__ h2b, float* __restrict__ el2, float* __restrict__ er2){
    __shared__ float sW[HD1 * NC];   // 8 KB
    __shared__ float sX[16 * HD1];   // 8 KB
    int t = threadIdx.x;
    for (int i = t; i < (HD1 * NC) / 4; i += 256)
        ((float4*)sW)[i] = ((const float4*)W2)[i];
    int r = t >> 4, c = t & 15;
    float a2 = al2[c], r2 = ar2[c];
    for (int g = blockIdx.x; g * 16 < N_NODES; g += gridDim.x){
        int rowb = g * 16;
        __syncthreads();
        {
            ushort4 v = ((const ushort4*)(x2b + (size_t)rowb * HD1))[t * 2];
            ushort4 v2 = ((const ushort4*)(x2b + (size_t)rowb * HD1))[t * 2 + 1];
            float4 f0 = { bf2f(v.x), bf2f(v.y), bf2f(v.z), bf2f(v.w) };
            float4 f1 = { bf2f(v2.x), bf2f(v2.y), bf2f(v2.z), bf2f(v2.w) };
            ((float4*)sX)[t * 2] = f0;
            ((float4*)sX)[t * 2 + 1] = f1;
        }
        __syncthreads();
        float acc = 0.f;
        #pragma unroll 8
        for (int k = 0; k < HD1; k++)
            acc += sX[r * HD1 + k] * sW[k * NC + c];
        int row = rowb + r;
        h2b[row * NC + c] = f2bf(acc);
        float pe = acc * a2, pr = acc * r2;
        #pragma unroll
        for (int d = 1; d < 16; d <<= 1){ pe += __shfl_xor(pe, d); pr += __shfl_xor(pr, d); }
        if (c == 0){ el2[row] = pe; er2[row] = pr; }
    }
}

// ---------------- Layer-2 aggregation + bias + log_softmax ----------------

__global__ void __launch_bounds__(256) k_agg2(const int* __restrict__ off, const int* __restrict__ csr_src,
                                              const float* __restrict__ el2, const float* __restrict__ er2,
                                              const unsigned short* __restrict__ h2b, const float* __restrict__ b2,
                                              float* __restrict__ out){
    int t = threadIdx.x;
    int sub = t >> 4;          // 16 nodes per block
    int c = t & 15;
    int n = blockIdx.x * 16 + sub;
    if (n >= N_NODES) return;
    int jb = off[n], je = off[n + 1];
    float er = er2[n];
    float accA = 0.f, accB = 0.f, wsA = 0.f, wsB = 0.f;
    int j = jb;
    for (; j + 1 < je; j += 2){
        int s0 = csr_src[j];
        int s1 = csr_src[j + 1];
        float w0 = __expf(leaky(el2[s0] + er));
        float w1 = __expf(leaky(el2[s1] + er));
        float v0 = bf2f(h2b[(size_t)s0 * NC + c]);
        float v1 = bf2f(h2b[(size_t)s1 * NC + c]);
        wsA += w0; accA += w0 * v0;
        wsB += w1; accB += w1 * v1;
    }
    if (j < je){
        int s0 = csr_src[j];
        float w0 = __expf(leaky(el2[s0] + er));
        wsA += w0; accA += w0 * bf2f(h2b[(size_t)s0 * NC + c]);
    }
    float acc = accA + accB, wsum = wsA + wsB;
    float o = (je > jb) ? acc / wsum : 0.f;
    o += b2[c];
    // log_softmax over the 16 classes (16-lane group)
    float m = o;
    #pragma unroll
    for (int d = 1; d < 16; d <<= 1) m = fmaxf(m, __shfl_xor(m, d));
    float ex = __expf(o - m);
    #pragma unroll
    for (int d = 1; d < 16; d <<= 1) ex += __shfl_xor(ex, d);
    out[(size_t)n * NC + c] = o - m - __logf(ex);
}

// ---------------- launch ----------------

extern "C" void kernel_launch(void* const* d_in, const int* in_sizes, int n_in,
                              void* d_out, int out_size, void* d_ws, size_t ws_size,
                              hipStream_t stream){
    const float* feat = (const float*)d_in[0];
    const int*   src  = (const int*)d_in[1];
    const int*   dst  = (const int*)d_in[2];
    const float* W1   = (const float*)d_in[3];
    const float* al1  = (const float*)d_in[4];
    const float* ar1  = (const float*)d_in[5];
    const float* b1   = (const float*)d_in[6];
    const float* W2   = (const float*)d_in[7];
    const float* al2  = (const float*)d_in[8];
    const float* ar2  = (const float*)d_in[9];
    const float* b2   = (const float*)d_in[10];
    float* out = (float*)d_out;

    char* w = (char*)d_ws;
    auto alloc = [&](size_t bytes) -> char* {
        char* p = w;
        w += (bytes + 255) & ~(size_t)255;
        return p;
    };
    int*   off      = (int*)alloc((size_t)(N_NODES + 1) * 4);
    int*   csr_src  = (int*)alloc((size_t)N_EDGES * 4);
    unsigned long long* pairs = (unsigned long long*)alloc((size_t)N_EDGES * 8);
    int*   bucketTotal  = (int*)alloc((size_t)(NBKT + 1) * 4);
    int*   bucketBase   = (int*)alloc((size_t)(NBKT + 1) * 4);
    int*   bucketCursor = (int*)alloc((size_t)(NBKT + 1) * 4);
    unsigned char*  h1f8 = (unsigned char*)alloc((size_t)N_NODES * HD1);
    unsigned short* el1b = (unsigned short*)alloc((size_t)N_NODES * HEADS * 2);
    float* er1v    = (float*)alloc((size_t)N_NODES * HEADS * 4);
    unsigned short* x2b = (unsigned short*)alloc((size_t)N_NODES * HD1 * 2);
    unsigned short* h2b = (unsigned short*)alloc((size_t)N_NODES * NC * 2);
    float* el2v    = (float*)alloc((size_t)N_NODES * 4);
    float* er2v    = (float*)alloc((size_t)N_NODES * 4);
    short* WTH     = (short*)alloc((size_t)F_IN * HD1 * 2);

    // CSR build (bucketed two-pass, no random global scatter)
    hipMemsetAsync(bucketTotal, 0, (size_t)(NBKT + 1) * 4, stream);
    k_p1hist<<<P1_BLOCKS, 256, 0, stream>>>(dst, bucketTotal);
    k_p1scan<<<1, 256, 0, stream>>>(bucketTotal, bucketBase, bucketCursor, off);
    k_p1bin<<<P1_BLOCKS, 256, 0, stream>>>(src, dst, bucketCursor, pairs);
    k_p2place<<<NBKT, 256, 0, stream>>>(pairs, bucketBase, off, csr_src);

    // Layer 1 compute
    k_splitW<<<(F_IN * HD1 + 255) / 256, 256, 0, stream>>>(W1, WTH);
    dim3 g1((N_NODES + 127) / 128, 2);
    k_gemm1m<<<g1, 256, 0, stream>>>(feat, WTH, h1f8);
    k_attn1<<<(N_NODES * HEADS + 255) / 256, 256, 0, stream>>>(h1f8, al1, ar1, el1b, er1v);

    // Layer-1 aggregation
    k_agg1<<<(N_NODES + 3) / 4, 256, 0, stream>>>(off, csr_src, el1b, er1v, h1f8, b1, x2b);

    // Layer 2
    k_gemm2<<<1024, 256, 0, stream>>>(x2b, W2, al2, ar2, h2b, el2v, er2v);
    k_agg2<<<(N_NODES + 15) / 16, 256, 0, stream>>>(off, csr_src, el2v, er2v, h2b, b2, out);
}

// Round 10
// 237.179 us; speedup vs baseline: 1.6949x; 1.0145x over previous
//
#include <hip/hip_runtime.h>

#define N_NODES 100000
#define N_EDGES 1600000
#define F_IN 256
#define HD1 128   // HEADS*HID
#define HEADS 8
#define HID 16
#define NC 16
#define NEG_SLOPE 0.2f
#define LOG2E 1.44269504f

// ---- bucketed CSR build params ----
#define BKT_NODES 512
#define NBKT ((N_NODES + BKT_NODES - 1) / BKT_NODES)   // 196
#define P1_EPB 8192
#define P1_BLOCKS ((N_EDGES + P1_EPB - 1) / P1_EPB)    // 196

__device__ __forceinline__ float leaky(float x){ return x > 0.f ? x : NEG_SLOPE * x; }
__device__ __forceinline__ unsigned short f2bf(float f){
    unsigned u = __float_as_uint(f);
    u += 0x7fff + ((u >> 16) & 1);       // round-to-nearest-even
    return (unsigned short)(u >> 16);
}
__device__ __forceinline__ float bf2f(unsigned short s){
    return __uint_as_float((unsigned)s << 16);
}
__device__ __forceinline__ unsigned char f2fp8(float v){
    return (unsigned char)(__builtin_amdgcn_cvt_pk_fp8_f32(v, v, 0, false) & 0xff);
}
// hardware packed fp32->bf16 (RNE), 2 floats -> 1 dword
__device__ __forceinline__ unsigned cvtpk_bf16(float lo, float hi){
    unsigned r;
    asm("v_cvt_pk_bf16_f32 %0, %1, %2" : "=v"(r) : "v"(lo), "v"(hi));
    return r;
}

typedef __bf16 bf16x8 __attribute__((ext_vector_type(8)));
typedef short short8 __attribute__((ext_vector_type(8)));
typedef float f32x4 __attribute__((ext_vector_type(4)));
typedef float f32x2 __attribute__((ext_vector_type(2)));

// ---------------- CSR build: bucketed, no random global scatter ----------------

__global__ void __launch_bounds__(256) k_p1hist(const int* __restrict__ dst, int* __restrict__ bucketTotal){
    __shared__ int h[NBKT];
    int t = threadIdx.x;
    for (int i = t; i < NBKT; i += 256) h[i] = 0;
    __syncthreads();
    int base = blockIdx.x * P1_EPB;
    int m = min(P1_EPB, N_EDGES - base);
    for (int i = t; i < m; i += 256) atomicAdd(&h[(unsigned)dst[base + i] >> 9], 1);
    __syncthreads();
    for (int i = t; i < NBKT; i += 256) if (h[i]) atomicAdd(&bucketTotal[i], h[i]);
}

__global__ void __launch_bounds__(256) k_p1scan(const int* __restrict__ bucketTotal,
                                                int* __restrict__ bucketBase, int* __restrict__ bucketCursor,
                                                int* __restrict__ off){
    __shared__ int sc[256];
    int t = threadIdx.x;
    int v = (t < NBKT) ? bucketTotal[t] : 0;
    sc[t] = v; __syncthreads();
    for (int o = 1; o < 256; o <<= 1){
        int a = (t >= o) ? sc[t - o] : 0;
        __syncthreads();
        sc[t] += a;
        __syncthreads();
    }
    if (t < NBKT){
        int b = sc[t] - v;         // exclusive
        bucketBase[t] = b;
        bucketCursor[t] = b;
    }
    if (t == 0){ bucketBase[NBKT] = N_EDGES; off[N_NODES] = N_EDGES; }
}

__global__ void __launch_bounds__(256) k_p1bin(const int* __restrict__ src, const int* __restrict__ dst,
                                               int* __restrict__ bucketCursor,
                                               unsigned long long* __restrict__ pairs){
    __shared__ unsigned long long pl[P1_EPB];   // 64 KB
    __shared__ int h[NBKT];                     // hist -> running cursor
    __shared__ int dl[NBKT];                    // global-base minus local-base
    __shared__ int sc[256];
    int t = threadIdx.x;
    for (int i = t; i < NBKT; i += 256) h[i] = 0;
    __syncthreads();
    int base = blockIdx.x * P1_EPB;
    int m = min(P1_EPB, N_EDGES - base);
    for (int i = t; i < m; i += 256) atomicAdd(&h[(unsigned)dst[base + i] >> 9], 1);
    __syncthreads();
    int v = (t < NBKT) ? h[t] : 0;
    sc[t] = v; __syncthreads();
    for (int o = 1; o < 256; o <<= 1){
        int a = (t >= o) ? sc[t - o] : 0;
        __syncthreads();
        sc[t] += a;
        __syncthreads();
    }
    if (t < NBKT){
        int ex = sc[t] - v;                        // local exclusive base
        int gb = v ? atomicAdd(&bucketCursor[t], v) : 0;
        dl[t] = gb - ex;
        h[t] = ex;                                 // reuse as running local cursor
    }
    __syncthreads();
    for (int i = t; i < m; i += 256){
        int d = dst[base + i], s = src[base + i];
        int b = (unsigned)d >> 9;
        int p = atomicAdd(&h[b], 1);
        pl[p] = ((unsigned long long)(unsigned)d << 32) | (unsigned)s;
    }
    __syncthreads();
    for (int i = t; i < m; i += 256){
        unsigned long long pr = pl[i];
        int b = (unsigned)(pr >> 32) >> 9;
        pairs[i + dl[b]] = pr;                     // sequential-run writes
    }
}

__global__ void __launch_bounds__(256) k_p2place(const unsigned long long* __restrict__ pairs,
                                                 const int* __restrict__ bucketBase,
                                                 int* __restrict__ off, int* __restrict__ csr_src){
    __shared__ int degc[BKT_NODES];
    __shared__ int sc2[BKT_NODES];
    int t = threadIdx.x;
    int b = blockIdx.x;
    int node0 = b * BKT_NODES;
    int nmax = min(BKT_NODES, N_NODES - node0);
    int p0 = bucketBase[b], p1 = bucketBase[b + 1];
    int m = p1 - p0;
    for (int i = t; i < BKT_NODES; i += 256) degc[i] = 0;
    __syncthreads();
    for (int i = t; i < m; i += 256){
        int d = (int)(pairs[p0 + i] >> 32) - node0;
        atomicAdd(&degc[d], 1);
    }
    __syncthreads();
    for (int i = t; i < BKT_NODES; i += 256) sc2[i] = degc[i];
    __syncthreads();
    // Hillis-Steele inclusive scan over 512 with 256 threads
    for (int o = 1; o < BKT_NODES; o <<= 1){
        int i0 = t, i1 = t + 256;
        int a0 = (i0 >= o) ? sc2[i0 - o] : 0;
        int a1 = (i1 >= o) ? sc2[i1 - o] : 0;
        __syncthreads();
        sc2[i0] += a0; sc2[i1] += a1;
        __syncthreads();
    }
    for (int i = t; i < BKT_NODES; i += 256){
        int cur = p0 + sc2[i] - degc[i];           // global exclusive offset
        if (i < nmax) off[node0 + i] = cur;
        degc[i] = cur;                              // becomes global cursor
    }
    __syncthreads();
    for (int i = t; i < m; i += 256){
        unsigned long long pr = pairs[p0 + i];
        int d = (int)(pr >> 32) - node0;
        int pos = atomicAdd(&degc[d], 1);
        csr_src[pos] = (int)(unsigned)pr;          // random only within 32KB window
    }
}

// ---------------- W1 -> bf16, transpose + XOR-swizzle ----------------

__global__ void __launch_bounds__(256) k_splitW(const float* __restrict__ W1,
                                                short* __restrict__ WTH){
    int i = blockIdx.x * 256 + threadIdx.x;   // 32768 elems
    if (i >= F_IN * HD1) return;
    int k = i >> 7, n = i & 127;
    int idx = n * 256 + (k ^ ((n & 7) << 3));
    WTH[idx] = (short)f2bf(W1[i]);
}

// ---------------- GEMM1 (MFMA bf16): h1f8 = fp8(feat @ W1) ----------------
// A-side fp32->bf16 via v_cvt_pk_bf16_f32 (hardware pack, 4 instr per 8 floats).

__device__ __forceinline__ short8 pack8(float4 f0, float4 f1){
    uint4 p;
    p.x = cvtpk_bf16(f0.x, f0.y);
    p.y = cvtpk_bf16(f0.z, f0.w);
    p.z = cvtpk_bf16(f1.x, f1.y);
    p.w = cvtpk_bf16(f1.z, f1.w);
    return __builtin_bit_cast(short8, p);
}

__global__ void __launch_bounds__(256, 4) k_gemm1m(const float* __restrict__ feat,
                                                   const short* __restrict__ WTH,
                                                   unsigned char* __restrict__ h1f8){
    __shared__ short sWH[64 * 256];   // 32 KB
    int t = threadIdx.x;
    int ch = blockIdx.y;
    {
        const short8* gh = (const short8*)(WTH + (size_t)ch * 16384);
        short8* sh = (short8*)sWH;
        for (int i = t; i < 2048; i += 256) sh[i] = gh[i];
    }
    __syncthreads();

    int wid = t >> 6, lane = t & 63;
    int m16 = lane & 15, kg = lane >> 4;
    int rowb = blockIdx.x * 128 + wid * 32;

    f32x4 acc[2][4];
    #pragma unroll
    for (int a = 0; a < 2; a++)
        #pragma unroll
        for (int b = 0; b < 4; b++)
            acc[a][b] = (f32x4){0.f, 0.f, 0.f, 0.f};

    int r0 = rowb + m16;       if (r0 > N_NODES - 1) r0 = N_NODES - 1;
    int r1 = rowb + 16 + m16;  if (r1 > N_NODES - 1) r1 = N_NODES - 1;
    const float* fp0 = feat + (size_t)r0 * F_IN;
    const float* fp1 = feat + (size_t)r1 * F_IN;

    #pragma unroll
    for (int ks = 0; ks < 8; ks++){
        int kbase = ks * 32 + kg * 8;
        short8 a0, a1;
        {
            const float4* p = (const float4*)(fp0 + kbase);
            a0 = pack8(p[0], p[1]);
        }
        {
            const float4* p = (const float4*)(fp1 + kbase);
            a1 = pack8(p[0], p[1]);
        }
        bf16x8 AH0 = __builtin_bit_cast(bf16x8, a0);
        bf16x8 AH1 = __builtin_bit_cast(bf16x8, a1);
        #pragma unroll
        for (int c = 0; c < 4; c++){
            int n = (c << 4) + m16;
            int kk = kbase ^ ((n & 7) << 3);
            bf16x8 bh = __builtin_bit_cast(bf16x8, *(const short8*)(sWH + n * 256 + kk));
            acc[0][c] = __builtin_amdgcn_mfma_f32_16x16x32_bf16(AH0, bh, acc[0][c], 0, 0, 0);
            acc[1][c] = __builtin_amdgcn_mfma_f32_16x16x32_bf16(AH1, bh, acc[1][c], 0, 0, 0);
        }
    }

    #pragma unroll
    for (int rf = 0; rf < 2; rf++){
        #pragma unroll
        for (int c = 0; c < 4; c++){
            #pragma unroll
            for (int r = 0; r < 4; r++){
                int row = rowb + rf * 16 + kg * 4 + r;
                if (row < N_NODES){
                    int col = ch * 64 + c * 16 + m16;
                    h1f8[(size_t)row * HD1 + col] = f2fp8(acc[rf][c][r]);
                }
            }
        }
    }
}

// ---------------- el1/er1 from h1f8 (pre-scaled by log2e; el1 bf16, er1 fp32) ----------------

__global__ void __launch_bounds__(256) k_attn1(const unsigned char* __restrict__ h1f8,
                                               const float* __restrict__ al1, const float* __restrict__ ar1,
                                               unsigned short* __restrict__ el1b, float* __restrict__ er1){
    int i = blockIdx.x * 256 + threadIdx.x;
    if (i >= N_NODES * HEADS) return;
    int n = i >> 3, h = i & 7;
    const unsigned* hp = (const unsigned*)(h1f8 + (size_t)n * HD1 + h * HID);
    float pe = 0.f, pr = 0.f;
    #pragma unroll
    for (int j = 0; j < 4; j++){
        unsigned u = hp[j];
        float x0 = __builtin_amdgcn_cvt_f32_fp8(u, 0);
        float x1 = __builtin_amdgcn_cvt_f32_fp8(u, 1);
        float x2 = __builtin_amdgcn_cvt_f32_fp8(u, 2);
        float x3 = __builtin_amdgcn_cvt_f32_fp8(u, 3);
        const float4 a = ((const float4*)(al1 + h * HID))[j];
        const float4 r = ((const float4*)(ar1 + h * HID))[j];
        pe += x0 * a.x + x1 * a.y + x2 * a.z + x3 * a.w;
        pr += x0 * r.x + x1 * r.y + x2 * r.z + x3 * r.w;
    }
    el1b[i] = f2bf(pe * LOG2E);      // leaky(k x)=k leaky(x): exp(leaky(e)) = exp2(leaky(e*log2e))
    er1[i] = pr * LOG2E;
}

// ---------------- Layer-1 aggregation: 1 wave/node, 16 lanes/edge, 4 edges/iter ----------------

__global__ void __launch_bounds__(256) k_agg1(const int* __restrict__ off, const int* __restrict__ csr_src,
                                              const unsigned short* __restrict__ el1b,
                                              const float* __restrict__ er1,
                                              const unsigned char* __restrict__ h1f8,
                                              const float* __restrict__ b1,
                                              unsigned short* __restrict__ x2b){
    int wid = threadIdx.x >> 6, lane = threadIdx.x & 63;
    int n = blockIdx.x * 4 + wid;
    if (n >= N_NODES) return;
    int jb = off[n], je = off[n + 1];
    int sub = lane >> 4;       // edge slot within quad (0..3)
    int q = lane & 15;         // column group: cols q*8 .. q*8+7
    int hh = q >> 1;           // head (2 lanes per head)
    float ern = er1[n * HEADS + hh];
    float a0=0.f,a1=0.f,a2=0.f,a3=0.f,a4=0.f,a5=0.f,a6=0.f,a7=0.f,wsum=0.f;

    #pragma unroll 2
    for (int j = jb; j < je; j += 4){
        int jj = j + sub;
        int jc = (jj < je) ? jj : je - 1;
        int s = csr_src[jc];
        float el = bf2f(el1b[s * HEADS + hh]);
        float wv = (jj < je) ? __builtin_amdgcn_exp2f(leaky(el + ern)) : 0.f;
        wsum += wv;
        uint2 u = *(const uint2*)(h1f8 + (((size_t)s) << 7) + (q << 3));
        f32x2 p0 = __builtin_amdgcn_cvt_pk_f32_fp8(u.x, 0);
        f32x2 p1 = __builtin_amdgcn_cvt_pk_f32_fp8(u.x, 1);
        f32x2 p2 = __builtin_amdgcn_cvt_pk_f32_fp8(u.y, 0);
        f32x2 p3 = __builtin_amdgcn_cvt_pk_f32_fp8(u.y, 1);
        a0 += wv * p0.x; a1 += wv * p0.y;
        a2 += wv * p1.x; a3 += wv * p1.y;
        a4 += wv * p2.x; a5 += wv * p2.y;
        a6 += wv * p3.x; a7 += wv * p3.y;
    }

    // reduce across the 4 edge-slots (lanes differing in bits 4,5)
    a0 += __shfl_xor(a0, 16); a0 += __shfl_xor(a0, 32);
    a1 += __shfl_xor(a1, 16); a1 += __shfl_xor(a1, 32);
    a2 += __shfl_xor(a2, 16); a2 += __shfl_xor(a2, 32);
    a3 += __shfl_xor(a3, 16); a3 += __shfl_xor(a3, 32);
    a4 += __shfl_xor(a4, 16); a4 += __shfl_xor(a4, 32);
    a5 += __shfl_xor(a5, 16); a5 += __shfl_xor(a5, 32);
    a6 += __shfl_xor(a6, 16); a6 += __shfl_xor(a6, 32);
    a7 += __shfl_xor(a7, 16); a7 += __shfl_xor(a7, 32);
    wsum += __shfl_xor(wsum, 16); wsum += __shfl_xor(wsum, 32);

    if (sub == 0){
        float inv = (je > jb) ? 1.f / wsum : 0.f;
        float o0 = a0*inv, o1 = a1*inv, o2 = a2*inv, o3 = a3*inv;
        float o4 = a4*inv, o5 = a5*inv, o6 = a6*inv, o7 = a7*inv;
        float4 bv0 = *(const float4*)(b1 + (q << 3));
        float4 bv1 = *(const float4*)(b1 + (q << 3) + 4);
        o0 += bv0.x; o1 += bv0.y; o2 += bv0.z; o3 += bv0.w;
        o4 += bv1.x; o5 += bv1.y; o6 += bv1.z; o7 += bv1.w;
        o0 = o0 > 0.f ? o0 : __expf(o0) - 1.f;
        o1 = o1 > 0.f ? o1 : __expf(o1) - 1.f;
        o2 = o2 > 0.f ? o2 : __expf(o2) - 1.f;
        o3 = o3 > 0.f ? o3 : __expf(o3) - 1.f;
        o4 = o4 > 0.f ? o4 : __expf(o4) - 1.f;
        o5 = o5 > 0.f ? o5 : __expf(o5) - 1.f;
        o6 = o6 > 0.f ? o6 : __expf(o6) - 1.f;
        o7 = o7 > 0.f ? o7 : __expf(o7) - 1.f;
        uint4 ov;
        ov.x = cvtpk_bf16(o0, o1);
        ov.y = cvtpk_bf16(o2, o3);
        ov.z = cvtpk_bf16(o4, o5);
        ov.w = cvtpk_bf16(o6, o7);
        *(uint4*)(x2b + (size_t)n * HD1 + (q << 3)) = ov;
    }
}

// ---------------- GEMM2: h2b = bf16(x2 @ W2), fused el2/er2 (pre-scaled) ----------------

__global__ void __launch_bounds__(256) k_gemm2(const unsigned short* __restrict__ x2b, const float* __restrict__ W2,
                                               const float* __restrict__ al2, const float* __restrict__ ar2,
                                               unsigned short* __restrict__ h2b, float* __restrict__ el2, float* __restrict__ er2){
    __shared__ float sW[HD1 * NC];   // 8 KB
    __shared__ float sX[16 * HD1];   // 8 KB
    int t = threadIdx.x;
    for (int i = t; i < (HD1 * NC) / 4; i += 256)
        ((float4*)sW)[i] = ((const float4*)W2)[i];
    int r = t >> 4, c = t & 15;
    float a2 = al2[c], r2 = ar2[c];
    for (int g = blockIdx.x; g * 16 < N_NODES; g += gridDim.x){
        int rowb = g * 16;
        __syncthreads();
        {
            ushort4 v = ((const ushort4*)(x2b + (size_t)rowb * HD1))[t * 2];
            ushort4 v2 = ((const ushort4*)(x2b + (size_t)rowb * HD1))[t * 2 + 1];
            float4 f0 = { bf2f(v.x), bf2f(v.y), bf2f(v.z), bf2f(v.w) };
            float4 f1 = { bf2f(v2.x), bf2f(v2.y), bf2f(v2.z), bf2f(v2.w) };
            ((float4*)sX)[t * 2] = f0;
            ((float4*)sX)[t * 2 + 1] = f1;
        }
        __syncthreads();
        float acc = 0.f;
        #pragma unroll 8
        for (int k = 0; k < HD1; k++)
            acc += sX[r * HD1 + k] * sW[k * NC + c];
        int row = rowb + r;
        h2b[row * NC + c] = f2bf(acc);
        float pe = acc * a2, pr = acc * r2;
        #pragma unroll
        for (int d = 1; d < 16; d <<= 1){ pe += __shfl_xor(pe, d); pr += __shfl_xor(pr, d); }
        if (c == 0){ el2[row] = pe * LOG2E; er2[row] = pr * LOG2E; }
    }
}

// ---------------- Layer-2 aggregation + bias + log_softmax ----------------

__global__ void __launch_bounds__(256) k_agg2(const int* __restrict__ off, const int* __restrict__ csr_src,
                                              const float* __restrict__ el2, const float* __restrict__ er2,
                                              const unsigned short* __restrict__ h2b, const float* __restrict__ b2,
                                              float* __restrict__ out){
    int t = threadIdx.x;
    int sub = t >> 4;          // 16 nodes per block
    int c = t & 15;
    int n = blockIdx.x * 16 + sub;
    if (n >= N_NODES) return;
    int jb = off[n], je = off[n + 1];
    float er = er2[n];
    float accA = 0.f, accB = 0.f, wsA = 0.f, wsB = 0.f;
    int j = jb;
    for (; j + 1 < je; j += 2){
        int s0 = csr_src[j];
        int s1 = csr_src[j + 1];
        float w0 = __builtin_amdgcn_exp2f(leaky(el2[s0] + er));
        float w1 = __builtin_amdgcn_exp2f(leaky(el2[s1] + er));
        float v0 = bf2f(h2b[(size_t)s0 * NC + c]);
        float v1 = bf2f(h2b[(size_t)s1 * NC + c]);
        wsA += w0; accA += w0 * v0;
        wsB += w1; accB += w1 * v1;
    }
    if (j < je){
        int s0 = csr_src[j];
        float w0 = __builtin_amdgcn_exp2f(leaky(el2[s0] + er));
        wsA += w0; accA += w0 * bf2f(h2b[(size_t)s0 * NC + c]);
    }
    float acc = accA + accB, wsum = wsA + wsB;
    float o = (je > jb) ? acc / wsum : 0.f;
    o += b2[c];
    // log_softmax over the 16 classes (16-lane group)
    float m = o;
    #pragma unroll
    for (int d = 1; d < 16; d <<= 1) m = fmaxf(m, __shfl_xor(m, d));
    float ex = __expf(o - m);
    #pragma unroll
    for (int d = 1; d < 16; d <<= 1) ex += __shfl_xor(ex, d);
    out[(size_t)n * NC + c] = o - m - __logf(ex);
}

// ---------------- launch ----------------

extern "C" void kernel_launch(void* const* d_in, const int* in_sizes, int n_in,
                              void* d_out, int out_size, void* d_ws, size_t ws_size,
                              hipStream_t stream){
    const float* feat = (const float*)d_in[0];
    const int*   src  = (const int*)d_in[1];
    const int*   dst  = (const int*)d_in[2];
    const float* W1   = (const float*)d_in[3];
    const float* al1  = (const float*)d_in[4];
    const float* ar1  = (const float*)d_in[5];
    const float* b1   = (const float*)d_in[6];
    const float* W2   = (const float*)d_in[7];
    const float* al2  = (const float*)d_in[8];
    const float* ar2  = (const float*)d_in[9];
    const float* b2   = (const float*)d_in[10];
    float* out = (float*)d_out;

    char* w = (char*)d_ws;
    auto alloc = [&](size_t bytes) -> char* {
        char* p = w;
        w += (bytes + 255) & ~(size_t)255;
        return p;
    };
    int*   off      = (int*)alloc((size_t)(N_NODES + 1) * 4);
    int*   csr_src  = (int*)alloc((size_t)N_EDGES * 4);
    unsigned long long* pairs = (unsigned long long*)alloc((size_t)N_EDGES * 8);
    int*   bucketTotal  = (int*)alloc((size_t)(NBKT + 1) * 4);
    int*   bucketBase   = (int*)alloc((size_t)(NBKT + 1) * 4);
    int*   bucketCursor = (int*)alloc((size_t)(NBKT + 1) * 4);
    unsigned char*  h1f8 = (unsigned char*)alloc((size_t)N_NODES * HD1);
    unsigned short* el1b = (unsigned short*)alloc((size_t)N_NODES * HEADS * 2);
    float* er1v    = (float*)alloc((size_t)N_NODES * HEADS * 4);
    unsigned short* x2b = (unsigned short*)alloc((size_t)N_NODES * HD1 * 2);
    unsigned short* h2b = (unsigned short*)alloc((size_t)N_NODES * NC * 2);
    float* el2v    = (float*)alloc((size_t)N_NODES * 4);
    float* er2v    = (float*)alloc((size_t)N_NODES * 4);
    short* WTH     = (short*)alloc((size_t)F_IN * HD1 * 2);

    // CSR build (bucketed two-pass, no random global scatter)
    hipMemsetAsync(bucketTotal, 0, (size_t)(NBKT + 1) * 4, stream);
    k_p1hist<<<P1_BLOCKS, 256, 0, stream>>>(dst, bucketTotal);
    k_p1scan<<<1, 256, 0, stream>>>(bucketTotal, bucketBase, bucketCursor, off);
    k_p1bin<<<P1_BLOCKS, 256, 0, stream>>>(src, dst, bucketCursor, pairs);
    k_p2place<<<NBKT, 256, 0, stream>>>(pairs, bucketBase, off, csr_src);

    // Layer 1 compute
    k_splitW<<<(F_IN * HD1 + 255) / 256, 256, 0, stream>>>(W1, WTH);
    dim3 g1((N_NODES + 127) / 128, 2);
    k_gemm1m<<<g1, 256, 0, stream>>>(feat, WTH, h1f8);
    k_attn1<<<(N_NODES * HEADS + 255) / 256, 256, 0, stream>>>(h1f8, al1, ar1, el1b, er1v);

    // Layer-1 aggregation
    k_agg1<<<(N_NODES + 3) / 4, 256, 0, stream>>>(off, csr_src, el1b, er1v, h1f8, b1, x2b);

    // Layer 2
    k_gemm2<<<1024, 256, 0, stream>>>(x2b, W2, al2, ar2, h2b, el2v, er2v);
    k_agg2<<<(N_NODES + 15) / 16, 256, 0, stream>>>(off, csr_src, el2v, er2v, h2b, b2, out);
}

// Round 11
// 233.908 us; speedup vs baseline: 1.7186x; 1.0140x over previous
//
#include <hip/hip_runtime.h>

#define N_NODES 100000
#define N_EDGES 1600000
#define F_IN 256
#define HD1 128   // HEADS*HID
#define HEADS 8
#define HID 16
#define NC 16
#define NEG_SLOPE 0.2f
#define LOG2E 1.44269504f

// ---- bucketed CSR build params ----
#define BKT_NODES 512
#define NBKT ((N_NODES + BKT_NODES - 1) / BKT_NODES)   // 196
#define P1_EPB 8192
#define P1_BLOCKS ((N_EDGES + P1_EPB - 1) / P1_EPB)    // 196

__device__ __forceinline__ float leaky(float x){ return x > 0.f ? x : NEG_SLOPE * x; }
__device__ __forceinline__ unsigned short f2bf(float f){
    unsigned u = __float_as_uint(f);
    u += 0x7fff + ((u >> 16) & 1);       // round-to-nearest-even
    return (unsigned short)(u >> 16);
}
__device__ __forceinline__ float bf2f(unsigned short s){
    return __uint_as_float((unsigned)s << 16);
}
__device__ __forceinline__ unsigned char f2fp8(float v){
    return (unsigned char)(__builtin_amdgcn_cvt_pk_fp8_f32(v, v, 0, false) & 0xff);
}
// hardware packed fp32->bf16 (RNE), 2 floats -> 1 dword
__device__ __forceinline__ unsigned cvtpk_bf16(float lo, float hi){
    unsigned r;
    asm("v_cvt_pk_bf16_f32 %0, %1, %2" : "=v"(r) : "v"(lo), "v"(hi));
    return r;
}

typedef __bf16 bf16x8 __attribute__((ext_vector_type(8)));
typedef short short8 __attribute__((ext_vector_type(8)));
typedef float f32x4 __attribute__((ext_vector_type(4)));
typedef float f32x2 __attribute__((ext_vector_type(2)));

// ---------------- CSR build: bucketed, no random global scatter ----------------

__global__ void __launch_bounds__(256) k_p1hist(const int* __restrict__ dst, int* __restrict__ bucketTotal){
    __shared__ int h[NBKT];
    int t = threadIdx.x;
    for (int i = t; i < NBKT; i += 256) h[i] = 0;
    __syncthreads();
    int base = blockIdx.x * P1_EPB;
    int m = min(P1_EPB, N_EDGES - base);
    for (int i = t; i < m; i += 256) atomicAdd(&h[(unsigned)dst[base + i] >> 9], 1);
    __syncthreads();
    for (int i = t; i < NBKT; i += 256) if (h[i]) atomicAdd(&bucketTotal[i], h[i]);
}

__global__ void __launch_bounds__(256) k_p1scan(const int* __restrict__ bucketTotal,
                                                int* __restrict__ bucketBase, int* __restrict__ bucketCursor,
                                                int* __restrict__ off){
    __shared__ int sc[256];
    int t = threadIdx.x;
    int v = (t < NBKT) ? bucketTotal[t] : 0;
    sc[t] = v; __syncthreads();
    for (int o = 1; o < 256; o <<= 1){
        int a = (t >= o) ? sc[t - o] : 0;
        __syncthreads();
        sc[t] += a;
        __syncthreads();
    }
    if (t < NBKT){
        int b = sc[t] - v;         // exclusive
        bucketBase[t] = b;
        bucketCursor[t] = b;
    }
    if (t == 0){ bucketBase[NBKT] = N_EDGES; off[N_NODES] = N_EDGES; }
}

__global__ void __launch_bounds__(256) k_p1bin(const int* __restrict__ src, const int* __restrict__ dst,
                                               int* __restrict__ bucketCursor,
                                               unsigned long long* __restrict__ pairs){
    __shared__ unsigned long long pl[P1_EPB];   // 64 KB
    __shared__ int h[NBKT];                     // hist -> running cursor
    __shared__ int dl[NBKT];                    // global-base minus local-base
    __shared__ int sc[256];
    int t = threadIdx.x;
    for (int i = t; i < NBKT; i += 256) h[i] = 0;
    __syncthreads();
    int base = blockIdx.x * P1_EPB;
    int m = min(P1_EPB, N_EDGES - base);
    for (int i = t; i < m; i += 256) atomicAdd(&h[(unsigned)dst[base + i] >> 9], 1);
    __syncthreads();
    int v = (t < NBKT) ? h[t] : 0;
    sc[t] = v; __syncthreads();
    for (int o = 1; o < 256; o <<= 1){
        int a = (t >= o) ? sc[t - o] : 0;
        __syncthreads();
        sc[t] += a;
        __syncthreads();
    }
    if (t < NBKT){
        int ex = sc[t] - v;                        // local exclusive base
        int gb = v ? atomicAdd(&bucketCursor[t], v) : 0;
        dl[t] = gb - ex;
        h[t] = ex;                                 // reuse as running local cursor
    }
    __syncthreads();
    for (int i = t; i < m; i += 256){
        int d = dst[base + i], s = src[base + i];
        int b = (unsigned)d >> 9;
        int p = atomicAdd(&h[b], 1);
        pl[p] = ((unsigned long long)(unsigned)d << 32) | (unsigned)s;
    }
    __syncthreads();
    for (int i = t; i < m; i += 256){
        unsigned long long pr = pl[i];
        int b = (unsigned)(pr >> 32) >> 9;
        pairs[i + dl[b]] = pr;                     // sequential-run writes
    }
}

__global__ void __launch_bounds__(256) k_p2place(const unsigned long long* __restrict__ pairs,
                                                 const int* __restrict__ bucketBase,
                                                 int* __restrict__ off, int* __restrict__ csr_src){
    __shared__ int degc[BKT_NODES];
    __shared__ int sc2[BKT_NODES];
    int t = threadIdx.x;
    int b = blockIdx.x;
    int node0 = b * BKT_NODES;
    int nmax = min(BKT_NODES, N_NODES - node0);
    int p0 = bucketBase[b], p1 = bucketBase[b + 1];
    int m = p1 - p0;
    for (int i = t; i < BKT_NODES; i += 256) degc[i] = 0;
    __syncthreads();
    for (int i = t; i < m; i += 256){
        int d = (int)(pairs[p0 + i] >> 32) - node0;
        atomicAdd(&degc[d], 1);
    }
    __syncthreads();
    for (int i = t; i < BKT_NODES; i += 256) sc2[i] = degc[i];
    __syncthreads();
    // Hillis-Steele inclusive scan over 512 with 256 threads
    for (int o = 1; o < BKT_NODES; o <<= 1){
        int i0 = t, i1 = t + 256;
        int a0 = (i0 >= o) ? sc2[i0 - o] : 0;
        int a1 = (i1 >= o) ? sc2[i1 - o] : 0;
        __syncthreads();
        sc2[i0] += a0; sc2[i1] += a1;
        __syncthreads();
    }
    for (int i = t; i < BKT_NODES; i += 256){
        int cur = p0 + sc2[i] - degc[i];           // global exclusive offset
        if (i < nmax) off[node0 + i] = cur;
        degc[i] = cur;                              // becomes global cursor
    }
    __syncthreads();
    for (int i = t; i < m; i += 256){
        unsigned long long pr = pairs[p0 + i];
        int d = (int)(pr >> 32) - node0;
        int pos = atomicAdd(&degc[d], 1);
        csr_src[pos] = (int)(unsigned)pr;          // random only within 32KB window
    }
}

// ---------------- W1 -> bf16, transpose + XOR-swizzle ----------------

__global__ void __launch_bounds__(256) k_splitW(const float* __restrict__ W1,
                                                short* __restrict__ WTH){
    int i = blockIdx.x * 256 + threadIdx.x;   // 32768 elems
    if (i >= F_IN * HD1) return;
    int k = i >> 7, n = i & 127;
    int idx = n * 256 + (k ^ ((n & 7) << 3));
    WTH[idx] = (short)f2bf(W1[i]);
}

// ---------------- GEMM1 (MFMA bf16): h1f8 = fp8(feat @ W1) ----------------
// Deep register pipeline: all 32 feat float4 loads issued up front (in-order VMEM
// returns -> descending vmcnt waits overlap compute). ~180 VGPR, 2 waves/SIMD.

__device__ __forceinline__ short8 pack8(float4 f0, float4 f1){
    uint4 p;
    p.x = cvtpk_bf16(f0.x, f0.y);
    p.y = cvtpk_bf16(f0.z, f0.w);
    p.z = cvtpk_bf16(f1.x, f1.y);
    p.w = cvtpk_bf16(f1.z, f1.w);
    return __builtin_bit_cast(short8, p);
}

__global__ void __launch_bounds__(256, 2) k_gemm1m(const float* __restrict__ feat,
                                                   const short* __restrict__ WTH,
                                                   unsigned char* __restrict__ h1f8){
    __shared__ short sWH[64 * 256];   // 32 KB
    int t = threadIdx.x;
    int ch = blockIdx.y;
    {
        const short8* gh = (const short8*)(WTH + (size_t)ch * 16384);
        short8* sh = (short8*)sWH;
        for (int i = t; i < 2048; i += 256) sh[i] = gh[i];
    }

    int wid = t >> 6, lane = t & 63;
    int m16 = lane & 15, kg = lane >> 4;
    int rowb = blockIdx.x * 128 + wid * 32;

    int r0 = rowb + m16;       if (r0 > N_NODES - 1) r0 = N_NODES - 1;
    int r1 = rowb + 16 + m16;  if (r1 > N_NODES - 1) r1 = N_NODES - 1;
    const float* fp0 = feat + (size_t)r0 * F_IN;
    const float* fp1 = feat + (size_t)r1 * F_IN;

    // issue the full feat burst (32x16B per thread) before the barrier;
    // W loads are older so their waits don't drain this queue.
    float4 s0[16], s1[16];
    #pragma unroll
    for (int ks = 0; ks < 8; ks++){
        const float4* p = (const float4*)(fp0 + ks * 32 + kg * 8);
        s0[2 * ks] = p[0]; s0[2 * ks + 1] = p[1];
    }
    #pragma unroll
    for (int ks = 0; ks < 8; ks++){
        const float4* p = (const float4*)(fp1 + ks * 32 + kg * 8);
        s1[2 * ks] = p[0]; s1[2 * ks + 1] = p[1];
    }

    __syncthreads();

    f32x4 acc[2][4];
    #pragma unroll
    for (int a = 0; a < 2; a++)
        #pragma unroll
        for (int b = 0; b < 4; b++)
            acc[a][b] = (f32x4){0.f, 0.f, 0.f, 0.f};

    #pragma unroll
    for (int ks = 0; ks < 8; ks++){
        int kbase = ks * 32 + kg * 8;
        bf16x8 AH0 = __builtin_bit_cast(bf16x8, pack8(s0[2 * ks], s0[2 * ks + 1]));
        bf16x8 AH1 = __builtin_bit_cast(bf16x8, pack8(s1[2 * ks], s1[2 * ks + 1]));
        #pragma unroll
        for (int c = 0; c < 4; c++){
            int n = (c << 4) + m16;
            int kk = kbase ^ ((n & 7) << 3);
            bf16x8 bh = __builtin_bit_cast(bf16x8, *(const short8*)(sWH + n * 256 + kk));
            acc[0][c] = __builtin_amdgcn_mfma_f32_16x16x32_bf16(AH0, bh, acc[0][c], 0, 0, 0);
            acc[1][c] = __builtin_amdgcn_mfma_f32_16x16x32_bf16(AH1, bh, acc[1][c], 0, 0, 0);
        }
    }

    #pragma unroll
    for (int rf = 0; rf < 2; rf++){
        #pragma unroll
        for (int c = 0; c < 4; c++){
            #pragma unroll
            for (int r = 0; r < 4; r++){
                int row = rowb + rf * 16 + kg * 4 + r;
                if (row < N_NODES){
                    int col = ch * 64 + c * 16 + m16;
                    h1f8[(size_t)row * HD1 + col] = f2fp8(acc[rf][c][r]);
                }
            }
        }
    }
}

// ---------------- el1/er1 from h1f8 (pre-scaled by log2e; el1 bf16, er1 fp32) ----------------

__global__ void __launch_bounds__(256) k_attn1(const unsigned char* __restrict__ h1f8,
                                               const float* __restrict__ al1, const float* __restrict__ ar1,
                                               unsigned short* __restrict__ el1b, float* __restrict__ er1){
    int i = blockIdx.x * 256 + threadIdx.x;
    if (i >= N_NODES * HEADS) return;
    int n = i >> 3, h = i & 7;
    const unsigned* hp = (const unsigned*)(h1f8 + (size_t)n * HD1 + h * HID);
    float pe = 0.f, pr = 0.f;
    #pragma unroll
    for (int j = 0; j < 4; j++){
        unsigned u = hp[j];
        float x0 = __builtin_amdgcn_cvt_f32_fp8(u, 0);
        float x1 = __builtin_amdgcn_cvt_f32_fp8(u, 1);
        float x2 = __builtin_amdgcn_cvt_f32_fp8(u, 2);
        float x3 = __builtin_amdgcn_cvt_f32_fp8(u, 3);
        const float4 a = ((const float4*)(al1 + h * HID))[j];
        const float4 r = ((const float4*)(ar1 + h * HID))[j];
        pe += x0 * a.x + x1 * a.y + x2 * a.z + x3 * a.w;
        pr += x0 * r.x + x1 * r.y + x2 * r.z + x3 * r.w;
    }
    el1b[i] = f2bf(pe * LOG2E);      // leaky(k x)=k leaky(x): exp(leaky(e)) = exp2(leaky(e*log2e))
    er1[i] = pr * LOG2E;
}

// ---------------- Layer-1 aggregation: 1 wave/node, 16 lanes/edge, 4 edges/iter ----------------

__global__ void __launch_bounds__(256) k_agg1(const int* __restrict__ off, const int* __restrict__ csr_src,
                                              const unsigned short* __restrict__ el1b,
                                              const float* __restrict__ er1,
                                              const unsigned char* __restrict__ h1f8,
                                              const float* __restrict__ b1,
                                              unsigned short* __restrict__ x2b){
    int wid = threadIdx.x >> 6, lane = threadIdx.x & 63;
    int n = blockIdx.x * 4 + wid;
    if (n >= N_NODES) return;
    int jb = off[n], je = off[n + 1];
    int sub = lane >> 4;       // edge slot within quad (0..3)
    int q = lane & 15;         // column group: cols q*8 .. q*8+7
    int hh = q >> 1;           // head (2 lanes per head)
    float ern = er1[n * HEADS + hh];
    float a0=0.f,a1=0.f,a2=0.f,a3=0.f,a4=0.f,a5=0.f,a6=0.f,a7=0.f,wsum=0.f;

    #pragma unroll 2
    for (int j = jb; j < je; j += 4){
        int jj = j + sub;
        int jc = (jj < je) ? jj : je - 1;
        int s = csr_src[jc];
        float el = bf2f(el1b[s * HEADS + hh]);
        float wv = (jj < je) ? __builtin_amdgcn_exp2f(leaky(el + ern)) : 0.f;
        wsum += wv;
        uint2 u = *(const uint2*)(h1f8 + (((size_t)s) << 7) + (q << 3));
        f32x2 p0 = __builtin_amdgcn_cvt_pk_f32_fp8(u.x, 0);
        f32x2 p1 = __builtin_amdgcn_cvt_pk_f32_fp8(u.x, 1);
        f32x2 p2 = __builtin_amdgcn_cvt_pk_f32_fp8(u.y, 0);
        f32x2 p3 = __builtin_amdgcn_cvt_pk_f32_fp8(u.y, 1);
        a0 += wv * p0.x; a1 += wv * p0.y;
        a2 += wv * p1.x; a3 += wv * p1.y;
        a4 += wv * p2.x; a5 += wv * p2.y;
        a6 += wv * p3.x; a7 += wv * p3.y;
    }

    // reduce across the 4 edge-slots (lanes differing in bits 4,5)
    a0 += __shfl_xor(a0, 16); a0 += __shfl_xor(a0, 32);
    a1 += __shfl_xor(a1, 16); a1 += __shfl_xor(a1, 32);
    a2 += __shfl_xor(a2, 16); a2 += __shfl_xor(a2, 32);
    a3 += __shfl_xor(a3, 16); a3 += __shfl_xor(a3, 32);
    a4 += __shfl_xor(a4, 16); a4 += __shfl_xor(a4, 32);
    a5 += __shfl_xor(a5, 16); a5 += __shfl_xor(a5, 32);
    a6 += __shfl_xor(a6, 16); a6 += __shfl_xor(a6, 32);
    a7 += __shfl_xor(a7, 16); a7 += __shfl_xor(a7, 32);
    wsum += __shfl_xor(wsum, 16); wsum += __shfl_xor(wsum, 32);

    if (sub == 0){
        float inv = (je > jb) ? 1.f / wsum : 0.f;
        float o0 = a0*inv, o1 = a1*inv, o2 = a2*inv, o3 = a3*inv;
        float o4 = a4*inv, o5 = a5*inv, o6 = a6*inv, o7 = a7*inv;
        float4 bv0 = *(const float4*)(b1 + (q << 3));
        float4 bv1 = *(const float4*)(b1 + (q << 3) + 4);
        o0 += bv0.x; o1 += bv0.y; o2 += bv0.z; o3 += bv0.w;
        o4 += bv1.x; o5 += bv1.y; o6 += bv1.z; o7 += bv1.w;
        o0 = o0 > 0.f ? o0 : __expf(o0) - 1.f;
        o1 = o1 > 0.f ? o1 : __expf(o1) - 1.f;
        o2 = o2 > 0.f ? o2 : __expf(o2) - 1.f;
        o3 = o3 > 0.f ? o3 : __expf(o3) - 1.f;
        o4 = o4 > 0.f ? o4 : __expf(o4) - 1.f;
        o5 = o5 > 0.f ? o5 : __expf(o5) - 1.f;
        o6 = o6 > 0.f ? o6 : __expf(o6) - 1.f;
        o7 = o7 > 0.f ? o7 : __expf(o7) - 1.f;
        uint4 ov;
        ov.x = cvtpk_bf16(o0, o1);
        ov.y = cvtpk_bf16(o2, o3);
        ov.z = cvtpk_bf16(o4, o5);
        ov.w = cvtpk_bf16(o6, o7);
        *(uint4*)(x2b + (size_t)n * HD1 + (q << 3)) = ov;
    }
}

// ---------------- GEMM2: h2b = bf16(x2 @ W2), fused el2/er2 (pre-scaled) ----------------

__global__ void __launch_bounds__(256) k_gemm2(const unsigned short* __restrict__ x2b, const float* __restrict__ W2,
                                               const float* __restrict__ al2, const float* __restrict__ ar2,
                                               unsigned short* __restrict__ h2b, float* __restrict__ el2, float* __restrict__ er2){
    __shared__ float sW[HD1 * NC];   // 8 KB
    __shared__ float sX[16 * HD1];   // 8 KB
    int t = threadIdx.x;
    for (int i = t; i < (HD1 * NC) / 4; i += 256)
        ((float4*)sW)[i] = ((const float4*)W2)[i];
    int r = t >> 4, c = t & 15;
    float a2 = al2[c], r2 = ar2[c];
    for (int g = blockIdx.x; g * 16 < N_NODES; g += gridDim.x){
        int rowb = g * 16;
        __syncthreads();
        {
            ushort4 v = ((const ushort4*)(x2b + (size_t)rowb * HD1))[t * 2];
            ushort4 v2 = ((const ushort4*)(x2b + (size_t)rowb * HD1))[t * 2 + 1];
            float4 f0 = { bf2f(v.x), bf2f(v.y), bf2f(v.z), bf2f(v.w) };
            float4 f1 = { bf2f(v2.x), bf2f(v2.y), bf2f(v2.z), bf2f(v2.w) };
            ((float4*)sX)[t * 2] = f0;
            ((float4*)sX)[t * 2 + 1] = f1;
        }
        __syncthreads();
        float acc = 0.f;
        #pragma unroll 8
        for (int k = 0; k < HD1; k++)
            acc += sX[r * HD1 + k] * sW[k * NC + c];
        int row = rowb + r;
        h2b[row * NC + c] = f2bf(acc);
        float pe = acc * a2, pr = acc * r2;
        #pragma unroll
        for (int d = 1; d < 16; d <<= 1){ pe += __shfl_xor(pe, d); pr += __shfl_xor(pr, d); }
        if (c == 0){ el2[row] = pe * LOG2E; er2[row] = pr * LOG2E; }
    }
}

// ---------------- Layer-2 aggregation + bias + log_softmax ----------------

__global__ void __launch_bounds__(256) k_agg2(const int* __restrict__ off, const int* __restrict__ csr_src,
                                              const float* __restrict__ el2, const float* __restrict__ er2,
                                              const unsigned short* __restrict__ h2b, const float* __restrict__ b2,
                                              float* __restrict__ out){
    int t = threadIdx.x;
    int sub = t >> 4;          // 16 nodes per block
    int c = t & 15;
    int n = blockIdx.x * 16 + sub;
    if (n >= N_NODES) return;
    int jb = off[n], je = off[n + 1];
    float er = er2[n];
    float accA = 0.f, accB = 0.f, wsA = 0.f, wsB = 0.f;
    int j = jb;
    for (; j + 1 < je; j += 2){
        int s0 = csr_src[j];
        int s1 = csr_src[j + 1];
        float w0 = __builtin_amdgcn_exp2f(leaky(el2[s0] + er));
        float w1 = __builtin_amdgcn_exp2f(leaky(el2[s1] + er));
        float v0 = bf2f(h2b[(size_t)s0 * NC + c]);
        float v1 = bf2f(h2b[(size_t)s1 * NC + c]);
        wsA += w0; accA += w0 * v0;
        wsB += w1; accB += w1 * v1;
    }
    if (j < je){
        int s0 = csr_src[j];
        float w0 = __builtin_amdgcn_exp2f(leaky(el2[s0] + er));
        wsA += w0; accA += w0 * bf2f(h2b[(size_t)s0 * NC + c]);
    }
    float acc = accA + accB, wsum = wsA + wsB;
    float o = (je > jb) ? acc / wsum : 0.f;
    o += b2[c];
    // log_softmax over the 16 classes (16-lane group)
    float m = o;
    #pragma unroll
    for (int d = 1; d < 16; d <<= 1) m = fmaxf(m, __shfl_xor(m, d));
    float ex = __expf(o - m);
    #pragma unroll
    for (int d = 1; d < 16; d <<= 1) ex += __shfl_xor(ex, d);
    out[(size_t)n * NC + c] = o - m - __logf(ex);
}

// ---------------- launch ----------------

extern "C" void kernel_launch(void* const* d_in, const int* in_sizes, int n_in,
                              void* d_out, int out_size, void* d_ws, size_t ws_size,
                              hipStream_t stream){
    const float* feat = (const float*)d_in[0];
    const int*   src  = (const int*)d_in[1];
    const int*   dst  = (const int*)d_in[2];
    const float* W1   = (const float*)d_in[3];
    const float* al1  = (const float*)d_in[4];
    const float* ar1  = (const float*)d_in[5];
    const float* b1   = (const float*)d_in[6];
    const float* W2   = (const float*)d_in[7];
    const float* al2  = (const float*)d_in[8];
    const float* ar2  = (const float*)d_in[9];
    const float* b2   = (const float*)d_in[10];
    float* out = (float*)d_out;

    char* w = (char*)d_ws;
    auto alloc = [&](size_t bytes) -> char* {
        char* p = w;
        w += (bytes + 255) & ~(size_t)255;
        return p;
    };
    int*   off      = (int*)alloc((size_t)(N_NODES + 1) * 4);
    int*   csr_src  = (int*)alloc((size_t)N_EDGES * 4);
    unsigned long long* pairs = (unsigned long long*)alloc((size_t)N_EDGES * 8);
    int*   bucketTotal  = (int*)alloc((size_t)(NBKT + 1) * 4);
    int*   bucketBase   = (int*)alloc((size_t)(NBKT + 1) * 4);
    int*   bucketCursor = (int*)alloc((size_t)(NBKT + 1) * 4);
    unsigned char*  h1f8 = (unsigned char*)alloc((size_t)N_NODES * HD1);
    unsigned short* el1b = (unsigned short*)alloc((size_t)N_NODES * HEADS * 2);
    float* er1v    = (float*)alloc((size_t)N_NODES * HEADS * 4);
    unsigned short* x2b = (unsigned short*)alloc((size_t)N_NODES * HD1 * 2);
    unsigned short* h2b = (unsigned short*)alloc((size_t)N_NODES * NC * 2);
    float* el2v    = (float*)alloc((size_t)N_NODES * 4);
    float* er2v    = (float*)alloc((size_t)N_NODES * 4);
    short* WTH     = (short*)alloc((size_t)F_IN * HD1 * 2);

    // CSR build (bucketed two-pass, no random global scatter)
    hipMemsetAsync(bucketTotal, 0, (size_t)(NBKT + 1) * 4, stream);
    k_p1hist<<<P1_BLOCKS, 256, 0, stream>>>(dst, bucketTotal);
    k_p1scan<<<1, 256, 0, stream>>>(bucketTotal, bucketBase, bucketCursor, off);
    k_p1bin<<<P1_BLOCKS, 256, 0, stream>>>(src, dst, bucketCursor, pairs);
    k_p2place<<<NBKT, 256, 0, stream>>>(pairs, bucketBase, off, csr_src);

    // Layer 1 compute
    k_splitW<<<(F_IN * HD1 + 255) / 256, 256, 0, stream>>>(W1, WTH);
    dim3 g1((N_NODES + 127) / 128, 2);
    k_gemm1m<<<g1, 256, 0, stream>>>(feat, WTH, h1f8);
    k_attn1<<<(N_NODES * HEADS + 255) / 256, 256, 0, stream>>>(h1f8, al1, ar1, el1b, er1v);

    // Layer-1 aggregation
    k_agg1<<<(N_NODES + 3) / 4, 256, 0, stream>>>(off, csr_src, el1b, er1v, h1f8, b1, x2b);

    // Layer 2
    k_gemm2<<<1024, 256, 0, stream>>>(x2b, W2, al2, ar2, h2b, el2v, er2v);
    k_agg2<<<(N_NODES + 15) / 16, 256, 0, stream>>>(off, csr_src, el2v, er2v, h2b, b2, out);
}